// Round 4
// baseline (6648.644 us; speedup 1.0000x reference)
//
#include <hip/hip_runtime.h>
#include <math.h>

#define TPB 256

// ---------------------------------------------------------------------------
// helpers
// ---------------------------------------------------------------------------
__device__ __forceinline__ float4 ld4(const float* p) { return *(const float4*)p; }

__device__ __forceinline__ void fma4(float s, const float4 w, float4& a) {
  a.x = fmaf(s, w.x, a.x); a.y = fmaf(s, w.y, a.y);
  a.z = fmaf(s, w.z, a.z); a.w = fmaf(s, w.w, a.w);
}

template<int C, int TPV>
__device__ __forceinline__ void dot4(const float* __restrict__ x,
                                     const float4* __restrict__ wp,
                                     float4& acc0, float4& acc1) {
  const float4* __restrict__ xp = (const float4*)x;
  #pragma unroll 8
  for (int c4 = 0; c4 < C / 4; ++c4) {
    const float4 xv = xp[c4];
    fma4(xv.x, wp[(c4 * 4 + 0) * TPV], acc0);
    fma4(xv.y, wp[(c4 * 4 + 1) * TPV], acc1);
    fma4(xv.z, wp[(c4 * 4 + 2) * TPV], acc0);
    fma4(xv.w, wp[(c4 * 4 + 3) * TPV], acc1);
  }
}

// 4 voxels x 4 co: each weight float4 feeds 16 FMAs
template<int C, int TPV>
__device__ __forceinline__ void dot4x4(const float* pa, const float* pb,
                                       const float* pc, const float* pd,
                                       const float4* __restrict__ wp,
                                       float4& A, float4& B, float4& Cc, float4& Dd) {
  const float4* a4 = (const float4*)pa;
  const float4* b4 = (const float4*)pb;
  const float4* c4 = (const float4*)pc;
  const float4* d4 = (const float4*)pd;
  #pragma unroll
  for (int k = 0; k < C / 4; ++k) {
    const float4 w0 = wp[(k * 4 + 0) * TPV];
    const float4 w1 = wp[(k * 4 + 1) * TPV];
    const float4 w2 = wp[(k * 4 + 2) * TPV];
    const float4 w3 = wp[(k * 4 + 3) * TPV];
    const float4 va = a4[k], vb = b4[k], vc = c4[k], vd = d4[k];
    fma4(va.x, w0, A);  fma4(va.y, w1, A);  fma4(va.z, w2, A);  fma4(va.w, w3, A);
    fma4(vb.x, w0, B);  fma4(vb.y, w1, B);  fma4(vb.z, w2, B);  fma4(vb.w, w3, B);
    fma4(vc.x, w0, Cc); fma4(vc.y, w1, Cc); fma4(vc.z, w2, Cc); fma4(vc.w, w3, Cc);
    fma4(vd.x, w0, Dd); fma4(vd.y, w1, Dd); fma4(vd.z, w2, Dd); fma4(vd.w, w3, Dd);
  }
}

template<int Co>
__device__ __forceinline__ float4 bn_relu(float4 a, const float* __restrict__ bn, int cg) {
  const float4 g = ld4(bn + cg * 4);
  const float4 b = ld4(bn + Co + cg * 4);
  const float4 m = ld4(bn + 2 * Co + cg * 4);
  const float4 v = ld4(bn + 3 * Co + cg * 4);
  float4 r;
  r.x = fmaxf((a.x - m.x) * (g.x * rsqrtf(v.x + 1e-5f)) + b.x, 0.f);
  r.y = fmaxf((a.y - m.y) * (g.y * rsqrtf(v.y + 1e-5f)) + b.y, 0.f);
  r.z = fmaxf((a.z - m.z) * (g.z * rsqrtf(v.z + 1e-5f)) + b.z, 0.f);
  r.w = fmaxf((a.w - m.w) * (g.w * rsqrtf(v.w + 1e-5f)) + b.w, 0.f);
  return r;
}

// ---------------------------------------------------------------------------
// mask pyramid
// ---------------------------------------------------------------------------
template<int LW, int LH, int D>   // coarse dims
__global__ void __launch_bounds__(TPB) k_maskpool(const float* __restrict__ mf,
                                                  float* __restrict__ mc) {
  constexpr int W = 1 << LW, H = 1 << LH;
  constexpr int total = D * H * W;
  const int v = blockIdx.x * TPB + threadIdx.x;
  if (v >= total) return;
  const int w = v & (W - 1), h = (v >> LW) & (H - 1), d = v >> (LW + LH);
  float mp = 0.f;
  #pragma unroll
  for (int dz = 0; dz < 2; ++dz)
    #pragma unroll
    for (int hz = 0; hz < 2; ++hz)
      #pragma unroll
      for (int wz = 0; wz < 2; ++wz)
        mp = fmaxf(mp, mf[((((2*d+dz) << (LH+1)) + (2*h+hz)) << (LW+1)) + (2*w+wz)]);
  mc[v] = mp;
}

// ---------------------------------------------------------------------------
// deterministic ordered compaction: count -> scan -> fill
// ---------------------------------------------------------------------------
__global__ void __launch_bounds__(TPB) k_count(const float* __restrict__ m, int total,
                                               int* __restrict__ bcount) {
  const int v = blockIdx.x * TPB + threadIdx.x;
  const bool act = (v < total) && (m[v] != 0.f);
  const unsigned long long b = __ballot(act);
  __shared__ int wc[TPB / 64];
  const int wid = threadIdx.x >> 6;
  if ((threadIdx.x & 63) == 0) wc[wid] = __popcll(b);
  __syncthreads();
  if (threadIdx.x == 0) bcount[blockIdx.x] = wc[0] + wc[1] + wc[2] + wc[3];
}

__global__ void __launch_bounds__(1024) k_scan(const int* __restrict__ bc, int nb,
                                               int* __restrict__ boff, int* __restrict__ total) {
  __shared__ int part[1024];
  const int t = threadIdx.x;
  const int a0 = (2 * t     < nb) ? bc[2 * t]     : 0;
  const int a1 = (2 * t + 1 < nb) ? bc[2 * t + 1] : 0;
  part[t] = a0 + a1;
  __syncthreads();
  for (int off = 1; off < 1024; off <<= 1) {
    const int tmp = (t >= off) ? part[t - off] : 0;
    __syncthreads();
    part[t] += tmp;
    __syncthreads();
  }
  const int excl = (t == 0) ? 0 : part[t - 1];
  if (2 * t     < nb) boff[2 * t]     = excl;
  if (2 * t + 1 < nb) boff[2 * t + 1] = excl + a0;
  if (t == 1023) *total = part[1023];
}

__global__ void __launch_bounds__(TPB) k_fill(const float* __restrict__ m, int total,
                                              const int* __restrict__ boff,
                                              int* __restrict__ list) {
  const int v = blockIdx.x * TPB + threadIdx.x;
  const bool act = (v < total) && (m[v] != 0.f);
  const unsigned long long b = __ballot(act);
  const int wid = threadIdx.x >> 6, lane = threadIdx.x & 63;
  __shared__ int wc[TPB / 64];
  __shared__ int wbase[TPB / 64];
  if (lane == 0) wc[wid] = __popcll(b);
  __syncthreads();
  if (threadIdx.x == 0) {
    int s = boff[blockIdx.x];
    #pragma unroll
    for (int i = 0; i < TPB / 64; ++i) { wbase[i] = s; s += wc[i]; }
  }
  __syncthreads();
  if (act) {
    const int rank = __popcll(b & ((1ull << lane) - 1ull));
    list[wbase[wid] + rank] = v;
  }
}

// ---------------------------------------------------------------------------
// subm V4: 3x3x3 SAME conv (+concat) + BN + ReLU over active list.
// thread = 4 consecutive list voxels x 4 co. Branch-free: inactive rows are
// zero (memset), OOB taps read zrow. Chunked XCD-contiguous scheduling.
// ---------------------------------------------------------------------------
template<int C1, int C2, int Co, int LW, int LH, int D>
__global__ void __launch_bounds__(TPB) k_subm_v(
    const float* __restrict__ x1, const float* __restrict__ x2,
    const float* __restrict__ wgt, const float* __restrict__ bn,
    const int* __restrict__ list, const int* __restrict__ cnt,
    const float* __restrict__ zrow, float* __restrict__ out)
{
  constexpr int Cin = C1 + C2;
  constexpr int TPV = Co / 4;
  constexpr int H = 1 << LH, W = 1 << LW;
  const int n = *cnt;
  const int nq = (n + 3) >> 2;
  const int total = nq * TPV;
  // bijective XCD-contiguous chunking: block (b&7) on xcd k gets chunk k*q+(b>>3)
  const unsigned nwg = gridDim.x;             // multiple of 8
  const unsigned q = nwg >> 3;
  const unsigned swz = (blockIdx.x & 7u) * q + (blockIdx.x >> 3);
  const int chunk = (total + (int)nwg - 1) / (int)nwg;
  const int beg = (int)swz * chunk;
  const int end = min(beg + chunk, total);
  for (int idx = beg + (int)threadIdx.x; idx < end; idx += TPB) {
    const int aq = idx / TPV;
    const int cg = idx % TPV;
    int vv[4], wx[4], hy[4], dz[4];
    #pragma unroll
    for (int j = 0; j < 4; ++j) {
      const int aa = min(aq * 4 + j, n - 1);
      const int v = list[aa];
      vv[j] = v;
      wx[j] = v & (W - 1); hy[j] = (v >> LW) & (H - 1); dz[j] = v >> (LW + LH);
    }
    float4 A  = make_float4(0.f, 0.f, 0.f, 0.f);
    float4 B  = make_float4(0.f, 0.f, 0.f, 0.f);
    float4 Cc = make_float4(0.f, 0.f, 0.f, 0.f);
    float4 Dd = make_float4(0.f, 0.f, 0.f, 0.f);
    for (int kd = 0; kd < 3; ++kd)
      for (int kh = 0; kh < 3; ++kh)
        for (int kw = 0; kw < 3; ++kw) {
          const int tap = (kd * 3 + kh) * 3 + kw;
          const float4* __restrict__ wp = (const float4*)wgt + (size_t)tap * Cin * TPV + cg;
          const float* p1[4];
          const float* p2[4];
          #pragma unroll
          for (int j = 0; j < 4; ++j) {
            const int zd0 = dz[j] + kd - 1, zh0 = hy[j] + kh - 1, zw0 = wx[j] + kw - 1;
            const bool inb = ((unsigned)zd0 < (unsigned)D) &
                             ((unsigned)zh0 < (unsigned)H) &
                             ((unsigned)zw0 < (unsigned)W);
            const int zd = min(max(zd0, 0), D - 1);
            const int zh = min(max(zh0, 0), H - 1);
            const int zw = min(max(zw0, 0), W - 1);
            const int nv = (((zd << LH) + zh) << LW) + zw;
            p1[j] = inb ? x1 + (size_t)nv * C1 : zrow;
            if constexpr (C2 > 0) p2[j] = inb ? x2 + (size_t)nv * C2 : zrow;
          }
          dot4x4<C1, TPV>(p1[0], p1[1], p1[2], p1[3], wp, A, B, Cc, Dd);
          if constexpr (C2 > 0)
            dot4x4<C2, TPV>(p2[0], p2[1], p2[2], p2[3], wp + C1 * TPV, A, B, Cc, Dd);
        }
    const int base = aq * 4;
    if (base + 0 < n) *(float4*)(out + (size_t)vv[0] * Co + cg * 4) = bn_relu<Co>(A,  bn, cg);
    if (base + 1 < n) *(float4*)(out + (size_t)vv[1] * Co + cg * 4) = bn_relu<Co>(B,  bn, cg);
    if (base + 2 < n) *(float4*)(out + (size_t)vv[2] * Co + cg * 4) = bn_relu<Co>(Cc, bn, cg);
    if (base + 3 < n) *(float4*)(out + (size_t)vv[3] * Co + cg * 4) = bn_relu<Co>(Dd, bn, cg);
  }
}

// ---------------------------------------------------------------------------
// down over coarse active list (2x2x2 stride-2 + BN + ReLU, fine-mask skip)
// ---------------------------------------------------------------------------
template<int Ci, int Co, int LW, int LH, int D>
__global__ void __launch_bounds__(TPB) k_down_a(
    const float* __restrict__ x, const float* __restrict__ wgt,
    const float* __restrict__ bn, const float* __restrict__ mfine,
    const int* __restrict__ list, const int* __restrict__ cnt,
    float* __restrict__ out)
{
  constexpr int TPV = Co / 4;
  constexpr int H = 1 << LH, W = 1 << LW;
  const int n = *cnt;
  const int total = n * TPV;
  for (int i = blockIdx.x * TPB + threadIdx.x; i < total; i += gridDim.x * TPB) {
    const int a = i / TPV;
    const int cg = i % TPV;
    const int v = list[a];
    const int w = v & (W - 1), h = (v >> LW) & (H - 1), d = v >> (LW + LH);
    float4 acc0 = make_float4(0.f, 0.f, 0.f, 0.f);
    float4 acc1 = make_float4(0.f, 0.f, 0.f, 0.f);
    #pragma unroll
    for (int kd = 0; kd < 2; ++kd)
      #pragma unroll
      for (int kh = 0; kh < 2; ++kh)
        #pragma unroll
        for (int kw = 0; kw < 2; ++kw) {
          const int nv = ((((2*d+kd) << (LH+1)) + (2*h+kh)) << (LW+1)) + (2*w+kw);
          if (mfine[nv] == 0.f) continue;
          const int tap = (kd * 2 + kh) * 2 + kw;
          const float4* __restrict__ wp = (const float4*)wgt + (size_t)tap * Ci * TPV + cg;
          dot4<Ci, TPV>(x + (size_t)nv * Ci, wp, acc0, acc1);
        }
    float4 acc;
    acc.x = acc0.x + acc1.x; acc.y = acc0.y + acc1.y;
    acc.z = acc0.z + acc1.z; acc.w = acc0.w + acc1.w;
    *(float4*)(out + (size_t)v * Co + cg * 4) = bn_relu<Co>(acc, bn, cg);
  }
}

// ---------------------------------------------------------------------------
// up over FINE active list: 1-tap conv_transpose
// ---------------------------------------------------------------------------
template<int Ci, int Co, int LW, int LH>
__global__ void __launch_bounds__(TPB) k_up_a(
    const float* __restrict__ x, const float* __restrict__ wgt,
    const int* __restrict__ list, const int* __restrict__ cnt,
    float* __restrict__ out)
{
  constexpr int TPV = Co / 4;
  constexpr int H = 1 << LH, W = 1 << LW;
  const int n = *cnt;
  const int total = n * TPV;
  for (int i = blockIdx.x * TPB + threadIdx.x; i < total; i += gridDim.x * TPB) {
    const int a = i / TPV;
    const int cg = i % TPV;
    const int v = list[a];
    const int w = v & (W - 1), h = (v >> LW) & (H - 1), d = v >> (LW + LH);
    const int kd = 1 - (d & 1), kh = 1 - (h & 1), kw = 1 - (w & 1);
    const int nv = ((((d >> 1) << (LH - 1)) + (h >> 1)) << (LW - 1)) + (w >> 1);
    const int tap = (kd * 2 + kh) * 2 + kw;
    const float4* __restrict__ wp = (const float4*)wgt + (size_t)tap * Ci * TPV + cg;
    float4 acc0 = make_float4(0.f, 0.f, 0.f, 0.f);
    float4 acc1 = make_float4(0.f, 0.f, 0.f, 0.f);
    dot4<Ci, TPV>(x + (size_t)nv * Ci, wp, acc0, acc1);
    float4 acc;
    acc.x = acc0.x + acc1.x; acc.y = acc0.y + acc1.y;
    acc.z = acc0.z + acc1.z; acc.w = acc0.w + acc1.w;
    *(float4*)(out + (size_t)v * Co + cg * 4) = acc;
  }
}

// ---------------------------------------------------------------------------
// head over active list
// ---------------------------------------------------------------------------
__global__ void __launch_bounds__(TPB) k_head_a(
    const float* __restrict__ c0, const float* __restrict__ wh,
    const float* __restrict__ bh, const int* __restrict__ list,
    const int* __restrict__ cnt, float* __restrict__ out)
{
  __shared__ float sw[32 * 45];
  __shared__ float sb[45];
  for (int t = threadIdx.x; t < 32 * 45; t += TPB) sw[t] = wh[t];
  if (threadIdx.x < 45) sb[threadIdx.x] = bh[threadIdx.x];
  __syncthreads();
  const int n = *cnt;
  const int total = n * 45;
  const size_t NV = 524288;
  for (int i = blockIdx.x * TPB + threadIdx.x; i < total; i += gridDim.x * TPB) {
    const int a = i / 45;
    const int j = i % 45;
    const int v = list[a];
    const float4* __restrict__ cp = (const float4*)(c0 + (size_t)v * 32);
    float a0 = 0.f, a1 = 0.f;
    #pragma unroll
    for (int c4 = 0; c4 < 8; ++c4) {
      const float4 xv = cp[c4];
      a0 = fmaf(xv.x, sw[(c4 * 4 + 0) * 45 + j], a0);
      a1 = fmaf(xv.y, sw[(c4 * 4 + 1) * 45 + j], a1);
      a0 = fmaf(xv.z, sw[(c4 * 4 + 2) * 45 + j], a0);
      a1 = fmaf(xv.w, sw[(c4 * 4 + 3) * 45 + j], a1);
    }
    const float val = a0 + a1 + sb[j];
    const int k = j / 9, r = j % 9;
    if (r < 3)
      out[(size_t)v * 15 + k * 3 + r] = val;
    else if (r < 6)
      out[NV * 15 + (size_t)v * 15 + k * 3 + (r - 3)] = fminf(fmaxf(val, -5.f), 3.f);
    else if (r == 6)
      out[NV * 30 + (size_t)v * 5 + k] = val;
    else if (r == 7)
      out[NV * 35 + (size_t)v * 5 + k] = val;
    else
      out[NV * 40 + (size_t)v * 5 + k] = val;
  }
}

// ---------------------------------------------------------------------------
extern "C" void kernel_launch(void* const* d_in, const int* in_sizes, int n_in,
                              void* d_out, int out_size, void* d_ws, size_t ws_size,
                              hipStream_t stream)
{
  (void)in_sizes; (void)n_in;

  const float* x        = (const float*)d_in[0];
  const float* mask0    = (const float*)d_in[1];
  const float* w_enc0   = (const float*)d_in[2];
  const float* bn_enc0  = (const float*)d_in[3];
  const float* w_down0  = (const float*)d_in[4];
  const float* bn_down0 = (const float*)d_in[5];
  const float* w_enc1   = (const float*)d_in[6];
  const float* bn_enc1  = (const float*)d_in[7];
  const float* w_down1  = (const float*)d_in[8];
  const float* bn_down1 = (const float*)d_in[9];
  const float* w_enc2   = (const float*)d_in[10];
  const float* bn_enc2  = (const float*)d_in[11];
  const float* w_down2  = (const float*)d_in[12];
  const float* bn_down2 = (const float*)d_in[13];
  const float* w_bott   = (const float*)d_in[14];
  const float* bn_bott  = (const float*)d_in[15];
  const float* w_up2    = (const float*)d_in[16];
  const float* w_dec2   = (const float*)d_in[17];
  const float* bn_dec2  = (const float*)d_in[18];
  const float* w_up1    = (const float*)d_in[19];
  const float* w_dec1   = (const float*)d_in[20];
  const float* bn_dec1  = (const float*)d_in[21];
  const float* w_up0    = (const float*)d_in[22];
  const float* w_dec0   = (const float*)d_in[23];
  const float* bn_dec0  = (const float*)d_in[24];
  const float* w_head   = (const float*)d_in[25];
  const float* b_head   = (const float*)d_in[26];

  float* ws = (float*)d_ws;
  size_t o = 0;
  auto take = [&](size_t nf) { float* p = ws + o; o += nf; return p; };

  int*   cnt   = (int*)take(16);
  int*   bcnt  = (int*)take(2048);
  int*   boff  = (int*)take(2048);
  int*   list0 = (int*)take(524288);
  int*   list1 = (int*)take(65536);
  int*   list2 = (int*)take(8192);
  int*   list3 = (int*)take(1024);
  float* zrow  = take(256);
  float* m1    = take(65536);
  float* m2    = take(8192);
  float* m3    = take(1024);
  float* e0 = take(16777216);
  float* d0 = take(4194304);              // reused as u1
  float* e1 = take(4194304);
  float* d1 = take(1048576);              // reused as u2
  float* e2 = take(1048576);
  float* d2 = take(262144);
  float* bb = take(262144);
  float* c2 = take(1048576);
  float* c1 = take(4194304);
  float* u0 = take(16777216);
  float* c0 = take(16777216);
  if (o * sizeof(float) > ws_size) return;
  float* u2 = d1;
  float* u1 = d0;
  int* cnt0 = cnt, *cnt1 = cnt + 1, *cnt2 = cnt + 2, *cnt3 = cnt + 3;

  // zero output + all gathered buffers (inactive rows must read as 0)
  hipMemsetAsync(d_out, 0, (size_t)out_size * sizeof(float), stream);
  hipMemsetAsync(zrow, 0, 256 * sizeof(float), stream);
  hipMemsetAsync(e0, 0, 16777216 * sizeof(float), stream);
  hipMemsetAsync(d0, 0, 4194304 * sizeof(float), stream);
  hipMemsetAsync(e1, 0, 4194304 * sizeof(float), stream);
  hipMemsetAsync(d1, 0, 1048576 * sizeof(float), stream);
  hipMemsetAsync(e2, 0, 1048576 * sizeof(float), stream);
  hipMemsetAsync(d2, 0, 262144 * sizeof(float), stream);
  hipMemsetAsync(u0, 0, 16777216 * sizeof(float), stream);

  auto g = [](long long upper) {
    unsigned b = (unsigned)((upper + TPB - 1) / TPB);
    return dim3(b > 4096u ? 4096u : (b ? b : 1u));
  };

  // mask pyramid
  k_maskpool<6, 6, 16><<<g(65536), TPB, 0, stream>>>(mask0, m1);
  k_maskpool<5, 5, 8><<<g(8192), TPB, 0, stream>>>(m1, m2);
  k_maskpool<4, 4, 4><<<g(1024), TPB, 0, stream>>>(m2, m3);

  // deterministic ordered compaction per level
  auto compact = [&](const float* m, int total, int* list, int* cptr) {
    const int nb = total / TPB;
    k_count<<<dim3((unsigned)nb), TPB, 0, stream>>>(m, total, bcnt);
    k_scan<<<dim3(1), 1024, 0, stream>>>(bcnt, nb, boff, cptr);
    k_fill<<<dim3((unsigned)nb), TPB, 0, stream>>>(m, total, boff, list);
  };
  compact(mask0, 524288, list0, cnt0);
  compact(m1,     65536, list1, cnt1);
  compact(m2,      8192, list2, cnt2);
  compact(m3,      1024, list3, cnt3);

  // grids for V4 subm kernels (multiple of 8; sized for ~expected density)
  const dim3 gs0(1024), gs1(1024), gs2(512), gs3(128);

  // encoder
  k_subm_v<20, 0, 32, 7, 7, 32><<<gs0, TPB, 0, stream>>>(x, nullptr, w_enc0, bn_enc0, list0, cnt0, zrow, e0);
  k_down_a<32, 64, 6, 6, 16><<<g(65536LL * 16), TPB, 0, stream>>>(e0, w_down0, bn_down0, mask0, list1, cnt1, d0);
  k_subm_v<64, 0, 64, 6, 6, 16><<<gs1, TPB, 0, stream>>>(d0, nullptr, w_enc1, bn_enc1, list1, cnt1, zrow, e1);
  k_down_a<64, 128, 5, 5, 8><<<g(8192LL * 32), TPB, 0, stream>>>(e1, w_down1, bn_down1, m1, list2, cnt2, d1);
  k_subm_v<128, 0, 128, 5, 5, 8><<<gs2, TPB, 0, stream>>>(d1, nullptr, w_enc2, bn_enc2, list2, cnt2, zrow, e2);
  k_down_a<128, 256, 4, 4, 4><<<g(1024LL * 64), TPB, 0, stream>>>(e2, w_down2, bn_down2, m2, list3, cnt3, d2);
  // bottleneck
  k_subm_v<256, 0, 256, 4, 4, 4><<<gs3, TPB, 0, stream>>>(d2, nullptr, w_bott, bn_bott, list3, cnt3, zrow, bb);
  // decoder
  k_up_a<256, 128, 5, 5><<<g(8192LL * 32), TPB, 0, stream>>>(bb, w_up2, list2, cnt2, u2);
  k_subm_v<128, 128, 128, 5, 5, 8><<<gs2, TPB, 0, stream>>>(u2, e2, w_dec2, bn_dec2, list2, cnt2, zrow, c2);
  k_up_a<128, 64, 6, 6><<<g(65536LL * 16), TPB, 0, stream>>>(c2, w_up1, list1, cnt1, u1);
  k_subm_v<64, 64, 64, 6, 6, 16><<<gs1, TPB, 0, stream>>>(u1, e1, w_dec1, bn_dec1, list1, cnt1, zrow, c1);
  k_up_a<64, 32, 7, 7><<<g(524288LL * 8), TPB, 0, stream>>>(c1, w_up0, list0, cnt0, u0);
  k_subm_v<32, 32, 32, 7, 7, 32><<<gs0, TPB, 0, stream>>>(u0, e0, w_dec0, bn_dec0, list0, cnt0, zrow, c0);
  // head
  k_head_a<<<g(524288LL * 45), TPB, 0, stream>>>(c0, w_head, b_head, list0, cnt0, (float*)d_out);
}

// Round 5
// 3563.071 us; speedup vs baseline: 1.8660x; 1.8660x over previous
//
#include <hip/hip_runtime.h>
#include <math.h>

#define TPB 256

// ---------------------------------------------------------------------------
// helpers
// ---------------------------------------------------------------------------
__device__ __forceinline__ float4 ld4(const float* p) { return *(const float4*)p; }

__device__ __forceinline__ void fma4(float s, const float4 w, float4& a) {
  a.x = fmaf(s, w.x, a.x); a.y = fmaf(s, w.y, a.y);
  a.z = fmaf(s, w.z, a.z); a.w = fmaf(s, w.w, a.w);
}

template<int C, int TPV>
__device__ __forceinline__ void dot4(const float* __restrict__ x,
                                     const float4* __restrict__ wp,
                                     float4& acc0, float4& acc1) {
  const float4* __restrict__ xp = (const float4*)x;
  #pragma unroll 8
  for (int c4 = 0; c4 < C / 4; ++c4) {
    const float4 xv = xp[c4];
    fma4(xv.x, wp[(c4 * 4 + 0) * TPV], acc0);
    fma4(xv.y, wp[(c4 * 4 + 1) * TPV], acc1);
    fma4(xv.z, wp[(c4 * 4 + 2) * TPV], acc0);
    fma4(xv.w, wp[(c4 * 4 + 3) * TPV], acc1);
  }
}

// 4 voxels x 4 co over a KC-deep channel chunk; weights from LDS (stride TPV float4)
template<int KC, int TPV>
__device__ __forceinline__ void dot4x4(const float* pa, const float* pb,
                                       const float* pc, const float* pd,
                                       const float4* wp,
                                       float4& A, float4& B, float4& Cc, float4& Dd) {
  const float4* a4 = (const float4*)pa;
  const float4* b4 = (const float4*)pb;
  const float4* c4 = (const float4*)pc;
  const float4* d4 = (const float4*)pd;
  #pragma unroll
  for (int k = 0; k < KC / 4; ++k) {
    const float4 w0 = wp[(k * 4 + 0) * TPV];
    const float4 w1 = wp[(k * 4 + 1) * TPV];
    const float4 w2 = wp[(k * 4 + 2) * TPV];
    const float4 w3 = wp[(k * 4 + 3) * TPV];
    const float4 va = a4[k], vb = b4[k], vc = c4[k], vd = d4[k];
    fma4(va.x, w0, A);  fma4(va.y, w1, A);  fma4(va.z, w2, A);  fma4(va.w, w3, A);
    fma4(vb.x, w0, B);  fma4(vb.y, w1, B);  fma4(vb.z, w2, B);  fma4(vb.w, w3, B);
    fma4(vc.x, w0, Cc); fma4(vc.y, w1, Cc); fma4(vc.z, w2, Cc); fma4(vc.w, w3, Cc);
    fma4(vd.x, w0, Dd); fma4(vd.y, w1, Dd); fma4(vd.z, w2, Dd); fma4(vd.w, w3, Dd);
  }
}

template<int Co>
__device__ __forceinline__ float4 bn_relu(float4 a, const float* __restrict__ bn, int cg) {
  const float4 g = ld4(bn + cg * 4);
  const float4 b = ld4(bn + Co + cg * 4);
  const float4 m = ld4(bn + 2 * Co + cg * 4);
  const float4 v = ld4(bn + 3 * Co + cg * 4);
  float4 r;
  r.x = fmaxf((a.x - m.x) * (g.x * rsqrtf(v.x + 1e-5f)) + b.x, 0.f);
  r.y = fmaxf((a.y - m.y) * (g.y * rsqrtf(v.y + 1e-5f)) + b.y, 0.f);
  r.z = fmaxf((a.z - m.z) * (g.z * rsqrtf(v.z + 1e-5f)) + b.z, 0.f);
  r.w = fmaxf((a.w - m.w) * (g.w * rsqrtf(v.w + 1e-5f)) + b.w, 0.f);
  return r;
}

// ---------------------------------------------------------------------------
// mask pyramid
// ---------------------------------------------------------------------------
template<int LW, int LH, int D>   // coarse dims
__global__ void __launch_bounds__(TPB) k_maskpool(const float* __restrict__ mf,
                                                  float* __restrict__ mc) {
  constexpr int W = 1 << LW, H = 1 << LH;
  constexpr int total = D * H * W;
  const int v = blockIdx.x * TPB + threadIdx.x;
  if (v >= total) return;
  const int w = v & (W - 1), h = (v >> LW) & (H - 1), d = v >> (LW + LH);
  float mp = 0.f;
  #pragma unroll
  for (int dz = 0; dz < 2; ++dz)
    #pragma unroll
    for (int hz = 0; hz < 2; ++hz)
      #pragma unroll
      for (int wz = 0; wz < 2; ++wz)
        mp = fmaxf(mp, mf[((((2*d+dz) << (LH+1)) + (2*h+hz)) << (LW+1)) + (2*w+wz)]);
  mc[v] = mp;
}

// ---------------------------------------------------------------------------
// deterministic ordered compaction: count -> scan -> fill
// ---------------------------------------------------------------------------
__global__ void __launch_bounds__(TPB) k_count(const float* __restrict__ m, int total,
                                               int* __restrict__ bcount) {
  const int v = blockIdx.x * TPB + threadIdx.x;
  const bool act = (v < total) && (m[v] != 0.f);
  const unsigned long long b = __ballot(act);
  __shared__ int wc[TPB / 64];
  const int wid = threadIdx.x >> 6;
  if ((threadIdx.x & 63) == 0) wc[wid] = __popcll(b);
  __syncthreads();
  if (threadIdx.x == 0) bcount[blockIdx.x] = wc[0] + wc[1] + wc[2] + wc[3];
}

__global__ void __launch_bounds__(1024) k_scan(const int* __restrict__ bc, int nb,
                                               int* __restrict__ boff, int* __restrict__ total) {
  __shared__ int part[1024];
  const int t = threadIdx.x;
  const int a0 = (2 * t     < nb) ? bc[2 * t]     : 0;
  const int a1 = (2 * t + 1 < nb) ? bc[2 * t + 1] : 0;
  part[t] = a0 + a1;
  __syncthreads();
  for (int off = 1; off < 1024; off <<= 1) {
    const int tmp = (t >= off) ? part[t - off] : 0;
    __syncthreads();
    part[t] += tmp;
    __syncthreads();
  }
  const int excl = (t == 0) ? 0 : part[t - 1];
  if (2 * t     < nb) boff[2 * t]     = excl;
  if (2 * t + 1 < nb) boff[2 * t + 1] = excl + a0;
  if (t == 1023) *total = part[1023];
}

__global__ void __launch_bounds__(TPB) k_fill(const float* __restrict__ m, int total,
                                              const int* __restrict__ boff,
                                              int* __restrict__ list) {
  const int v = blockIdx.x * TPB + threadIdx.x;
  const bool act = (v < total) && (m[v] != 0.f);
  const unsigned long long b = __ballot(act);
  const int wid = threadIdx.x >> 6, lane = threadIdx.x & 63;
  __shared__ int wc[TPB / 64];
  __shared__ int wbase[TPB / 64];
  if (lane == 0) wc[wid] = __popcll(b);
  __syncthreads();
  if (threadIdx.x == 0) {
    int s = boff[blockIdx.x];
    #pragma unroll
    for (int i = 0; i < TPB / 64; ++i) { wbase[i] = s; s += wc[i]; }
  }
  __syncthreads();
  if (act) {
    const int rank = __popcll(b & ((1ull << lane) - 1ull));
    list[wbase[wid] + rank] = v;
  }
}

// ---------------------------------------------------------------------------
// subm with LDS weight staging: 3x3x3 SAME conv (+concat) + BN + ReLU.
// Block = QPB voxel-quads x TPV co-groups. Per (tap, cin-chunk): block stages
// W[tap][chunk] (KC x Co <= 32 KB) into LDS once; threads consume via b128.
// Branch-free: inactive rows are zero (memset), OOB taps read zrow.
// ---------------------------------------------------------------------------
template<int C1, int C2, int Co, int KC, int LW, int LH, int D>
__global__ void __launch_bounds__(TPB) k_subm_t(
    const float* __restrict__ x1, const float* __restrict__ x2,
    const float* __restrict__ wgt, const float* __restrict__ bn,
    const int* __restrict__ list, const int* __restrict__ cnt,
    const float* __restrict__ zrow, float* __restrict__ out)
{
  constexpr int Cin = C1 + C2;
  constexpr int TPV = Co / 4;          // threads per quad
  constexpr int QPB = TPB / TPV;       // quads per block
  constexpr int NCH = Cin / KC;        // cin chunks per tap
  constexpr int NW4 = KC * Co / 4;     // float4s per staged chunk
  constexpr int H = 1 << LH, W = 1 << LW;
  __shared__ float sw[KC * Co];

  const int n = *cnt;
  const int nq = (n + 3) >> 2;
  if ((int)blockIdx.x * QPB >= nq) return;       // block-uniform exit
  const int q  = blockIdx.x * QPB + (int)(threadIdx.x / TPV);
  const int cg = threadIdx.x % TPV;
  const int qc = min(q, nq - 1);                 // tail threads duplicate last quad

  int vv[4], wx[4], hy[4], dz[4];
  #pragma unroll
  for (int j = 0; j < 4; ++j) {
    const int aa = min(qc * 4 + j, n - 1);
    const int v = list[aa];
    vv[j] = v; wx[j] = v & (W - 1); hy[j] = (v >> LW) & (H - 1); dz[j] = v >> (LW + LH);
  }
  float4 A  = make_float4(0.f, 0.f, 0.f, 0.f);
  float4 B  = make_float4(0.f, 0.f, 0.f, 0.f);
  float4 Cc = make_float4(0.f, 0.f, 0.f, 0.f);
  float4 Dd = make_float4(0.f, 0.f, 0.f, 0.f);

  for (int kd = 0; kd < 3; ++kd)
  for (int kh = 0; kh < 3; ++kh)
  for (int kw = 0; kw < 3; ++kw) {
    const int tap = (kd * 3 + kh) * 3 + kw;
    const float* r1[4];
    const float* r2[4];
    #pragma unroll
    for (int j = 0; j < 4; ++j) {
      const int zd0 = dz[j] + kd - 1, zh0 = hy[j] + kh - 1, zw0 = wx[j] + kw - 1;
      const bool inb = ((unsigned)zd0 < (unsigned)D) &
                       ((unsigned)zh0 < (unsigned)H) &
                       ((unsigned)zw0 < (unsigned)W);
      const int zd = min(max(zd0, 0), D - 1);
      const int zh = min(max(zh0, 0), H - 1);
      const int zw = min(max(zw0, 0), W - 1);
      const int nv = (((zd << LH) + zh) << LW) + zw;
      r1[j] = inb ? x1 + (size_t)nv * C1 : zrow;
      if constexpr (C2 > 0) r2[j] = inb ? x2 + (size_t)nv * C2 : zrow;
    }
    #pragma unroll
    for (int c = 0; c < NCH; ++c) {
      __syncthreads();  // previous chunk's LDS reads done
      {
        const float4* __restrict__ src =
            (const float4*)(wgt + ((size_t)tap * Cin + c * KC) * Co);
        float4* dst = (float4*)sw;
        #pragma unroll
        for (int t = 0; t < (NW4 + TPB - 1) / TPB; ++t) {
          const int ii = t * TPB + (int)threadIdx.x;
          if (NW4 % TPB == 0 || ii < NW4) dst[ii] = src[ii];
        }
      }
      __syncthreads();  // staged chunk visible
      const float4* wp = (const float4*)sw + cg;
      const int ci0 = c * KC;
      const float *pa, *pb, *pc, *pd;
      if (C2 == 0 || ci0 < C1) {
        pa = r1[0] + ci0; pb = r1[1] + ci0; pc = r1[2] + ci0; pd = r1[3] + ci0;
      } else {
        pa = r2[0] + (ci0 - C1); pb = r2[1] + (ci0 - C1);
        pc = r2[2] + (ci0 - C1); pd = r2[3] + (ci0 - C1);
      }
      dot4x4<KC, TPV>(pa, pb, pc, pd, wp, A, B, Cc, Dd);
    }
  }

  if (q < nq) {
    const int base = qc * 4;
    if (base + 0 < n) *(float4*)(out + (size_t)vv[0] * Co + cg * 4) = bn_relu<Co>(A,  bn, cg);
    if (base + 1 < n) *(float4*)(out + (size_t)vv[1] * Co + cg * 4) = bn_relu<Co>(B,  bn, cg);
    if (base + 2 < n) *(float4*)(out + (size_t)vv[2] * Co + cg * 4) = bn_relu<Co>(Cc, bn, cg);
    if (base + 3 < n) *(float4*)(out + (size_t)vv[3] * Co + cg * 4) = bn_relu<Co>(Dd, bn, cg);
  }
}

// ---------------------------------------------------------------------------
// down over coarse active list (2x2x2 stride-2 + BN + ReLU, fine-mask skip)
// ---------------------------------------------------------------------------
template<int Ci, int Co, int LW, int LH, int D>
__global__ void __launch_bounds__(TPB) k_down_a(
    const float* __restrict__ x, const float* __restrict__ wgt,
    const float* __restrict__ bn, const float* __restrict__ mfine,
    const int* __restrict__ list, const int* __restrict__ cnt,
    float* __restrict__ out)
{
  constexpr int TPV = Co / 4;
  constexpr int H = 1 << LH, W = 1 << LW;
  const int n = *cnt;
  const int total = n * TPV;
  for (int i = blockIdx.x * TPB + threadIdx.x; i < total; i += gridDim.x * TPB) {
    const int a = i / TPV;
    const int cg = i % TPV;
    const int v = list[a];
    const int w = v & (W - 1), h = (v >> LW) & (H - 1), d = v >> (LW + LH);
    float4 acc0 = make_float4(0.f, 0.f, 0.f, 0.f);
    float4 acc1 = make_float4(0.f, 0.f, 0.f, 0.f);
    #pragma unroll
    for (int kd = 0; kd < 2; ++kd)
      #pragma unroll
      for (int kh = 0; kh < 2; ++kh)
        #pragma unroll
        for (int kw = 0; kw < 2; ++kw) {
          const int nv = ((((2*d+kd) << (LH+1)) + (2*h+kh)) << (LW+1)) + (2*w+kw);
          if (mfine[nv] == 0.f) continue;
          const int tap = (kd * 2 + kh) * 2 + kw;
          const float4* __restrict__ wp = (const float4*)wgt + (size_t)tap * Ci * TPV + cg;
          dot4<Ci, TPV>(x + (size_t)nv * Ci, wp, acc0, acc1);
        }
    float4 acc;
    acc.x = acc0.x + acc1.x; acc.y = acc0.y + acc1.y;
    acc.z = acc0.z + acc1.z; acc.w = acc0.w + acc1.w;
    *(float4*)(out + (size_t)v * Co + cg * 4) = bn_relu<Co>(acc, bn, cg);
  }
}

// ---------------------------------------------------------------------------
// up over FINE active list: 1-tap conv_transpose
// ---------------------------------------------------------------------------
template<int Ci, int Co, int LW, int LH>
__global__ void __launch_bounds__(TPB) k_up_a(
    const float* __restrict__ x, const float* __restrict__ wgt,
    const int* __restrict__ list, const int* __restrict__ cnt,
    float* __restrict__ out)
{
  constexpr int TPV = Co / 4;
  constexpr int H = 1 << LH, W = 1 << LW;
  const int n = *cnt;
  const int total = n * TPV;
  for (int i = blockIdx.x * TPB + threadIdx.x; i < total; i += gridDim.x * TPB) {
    const int a = i / TPV;
    const int cg = i % TPV;
    const int v = list[a];
    const int w = v & (W - 1), h = (v >> LW) & (H - 1), d = v >> (LW + LH);
    const int kd = 1 - (d & 1), kh = 1 - (h & 1), kw = 1 - (w & 1);
    const int nv = ((((d >> 1) << (LH - 1)) + (h >> 1)) << (LW - 1)) + (w >> 1);
    const int tap = (kd * 2 + kh) * 2 + kw;
    const float4* __restrict__ wp = (const float4*)wgt + (size_t)tap * Ci * TPV + cg;
    float4 acc0 = make_float4(0.f, 0.f, 0.f, 0.f);
    float4 acc1 = make_float4(0.f, 0.f, 0.f, 0.f);
    dot4<Ci, TPV>(x + (size_t)nv * Ci, wp, acc0, acc1);
    float4 acc;
    acc.x = acc0.x + acc1.x; acc.y = acc0.y + acc1.y;
    acc.z = acc0.z + acc1.z; acc.w = acc0.w + acc1.w;
    *(float4*)(out + (size_t)v * Co + cg * 4) = acc;
  }
}

// ---------------------------------------------------------------------------
// head over active list
// ---------------------------------------------------------------------------
__global__ void __launch_bounds__(TPB) k_head_a(
    const float* __restrict__ c0, const float* __restrict__ wh,
    const float* __restrict__ bh, const int* __restrict__ list,
    const int* __restrict__ cnt, float* __restrict__ out)
{
  __shared__ float sw[32 * 45];
  __shared__ float sb[45];
  for (int t = threadIdx.x; t < 32 * 45; t += TPB) sw[t] = wh[t];
  if (threadIdx.x < 45) sb[threadIdx.x] = bh[threadIdx.x];
  __syncthreads();
  const int n = *cnt;
  const int total = n * 45;
  const size_t NV = 524288;
  for (int i = blockIdx.x * TPB + threadIdx.x; i < total; i += gridDim.x * TPB) {
    const int a = i / 45;
    const int j = i % 45;
    const int v = list[a];
    const float4* __restrict__ cp = (const float4*)(c0 + (size_t)v * 32);
    float a0 = 0.f, a1 = 0.f;
    #pragma unroll
    for (int c4 = 0; c4 < 8; ++c4) {
      const float4 xv = cp[c4];
      a0 = fmaf(xv.x, sw[(c4 * 4 + 0) * 45 + j], a0);
      a1 = fmaf(xv.y, sw[(c4 * 4 + 1) * 45 + j], a1);
      a0 = fmaf(xv.z, sw[(c4 * 4 + 2) * 45 + j], a0);
      a1 = fmaf(xv.w, sw[(c4 * 4 + 3) * 45 + j], a1);
    }
    const float val = a0 + a1 + sb[j];
    const int k = j / 9, r = j % 9;
    if (r < 3)
      out[(size_t)v * 15 + k * 3 + r] = val;
    else if (r < 6)
      out[NV * 15 + (size_t)v * 15 + k * 3 + (r - 3)] = fminf(fmaxf(val, -5.f), 3.f);
    else if (r == 6)
      out[NV * 30 + (size_t)v * 5 + k] = val;
    else if (r == 7)
      out[NV * 35 + (size_t)v * 5 + k] = val;
    else
      out[NV * 40 + (size_t)v * 5 + k] = val;
  }
}

// ---------------------------------------------------------------------------
extern "C" void kernel_launch(void* const* d_in, const int* in_sizes, int n_in,
                              void* d_out, int out_size, void* d_ws, size_t ws_size,
                              hipStream_t stream)
{
  (void)in_sizes; (void)n_in;

  const float* x        = (const float*)d_in[0];
  const float* mask0    = (const float*)d_in[1];
  const float* w_enc0   = (const float*)d_in[2];
  const float* bn_enc0  = (const float*)d_in[3];
  const float* w_down0  = (const float*)d_in[4];
  const float* bn_down0 = (const float*)d_in[5];
  const float* w_enc1   = (const float*)d_in[6];
  const float* bn_enc1  = (const float*)d_in[7];
  const float* w_down1  = (const float*)d_in[8];
  const float* bn_down1 = (const float*)d_in[9];
  const float* w_enc2   = (const float*)d_in[10];
  const float* bn_enc2  = (const float*)d_in[11];
  const float* w_down2  = (const float*)d_in[12];
  const float* bn_down2 = (const float*)d_in[13];
  const float* w_bott   = (const float*)d_in[14];
  const float* bn_bott  = (const float*)d_in[15];
  const float* w_up2    = (const float*)d_in[16];
  const float* w_dec2   = (const float*)d_in[17];
  const float* bn_dec2  = (const float*)d_in[18];
  const float* w_up1    = (const float*)d_in[19];
  const float* w_dec1   = (const float*)d_in[20];
  const float* bn_dec1  = (const float*)d_in[21];
  const float* w_up0    = (const float*)d_in[22];
  const float* w_dec0   = (const float*)d_in[23];
  const float* bn_dec0  = (const float*)d_in[24];
  const float* w_head   = (const float*)d_in[25];
  const float* b_head   = (const float*)d_in[26];

  float* ws = (float*)d_ws;
  size_t o = 0;
  auto take = [&](size_t nf) { float* p = ws + o; o += nf; return p; };

  int*   cnt   = (int*)take(16);
  int*   bcnt  = (int*)take(2048);
  int*   boff  = (int*)take(2048);
  int*   list0 = (int*)take(524288);
  int*   list1 = (int*)take(65536);
  int*   list2 = (int*)take(8192);
  int*   list3 = (int*)take(1024);
  float* zrow  = take(256);
  float* m1    = take(65536);
  float* m2    = take(8192);
  float* m3    = take(1024);
  float* e0 = take(16777216);
  float* d0 = take(4194304);              // reused as u1
  float* e1 = take(4194304);
  float* d1 = take(1048576);              // reused as u2
  float* e2 = take(1048576);
  float* d2 = take(262144);
  float* bb = take(262144);
  float* c2 = take(1048576);
  float* c1 = take(4194304);
  float* u0 = take(16777216);
  float* c0 = take(16777216);
  if (o * sizeof(float) > ws_size) return;
  float* u2 = d1;
  float* u1 = d0;
  int* cnt0 = cnt, *cnt1 = cnt + 1, *cnt2 = cnt + 2, *cnt3 = cnt + 3;

  // zero output + gathered buffers (inactive rows must read as 0)
  hipMemsetAsync(d_out, 0, (size_t)out_size * sizeof(float), stream);
  hipMemsetAsync(zrow, 0, 256 * sizeof(float), stream);
  hipMemsetAsync(e0, 0, 16777216 * sizeof(float), stream);
  hipMemsetAsync(d0, 0, 4194304 * sizeof(float), stream);
  hipMemsetAsync(e1, 0, 4194304 * sizeof(float), stream);
  hipMemsetAsync(d1, 0, 1048576 * sizeof(float), stream);
  hipMemsetAsync(e2, 0, 1048576 * sizeof(float), stream);
  hipMemsetAsync(d2, 0, 262144 * sizeof(float), stream);
  hipMemsetAsync(u0, 0, 16777216 * sizeof(float), stream);

  auto g = [](long long upper) {
    unsigned b = (unsigned)((upper + TPB - 1) / TPB);
    return dim3(b > 4096u ? 4096u : (b ? b : 1u));
  };

  // mask pyramid
  k_maskpool<6, 6, 16><<<g(65536), TPB, 0, stream>>>(mask0, m1);
  k_maskpool<5, 5, 8><<<g(8192), TPB, 0, stream>>>(m1, m2);
  k_maskpool<4, 4, 4><<<g(1024), TPB, 0, stream>>>(m2, m3);

  // deterministic ordered compaction per level
  auto compact = [&](const float* m, int total, int* list, int* cptr) {
    const int nb = total / TPB;
    k_count<<<dim3((unsigned)nb), TPB, 0, stream>>>(m, total, bcnt);
    k_scan<<<dim3(1), 1024, 0, stream>>>(bcnt, nb, boff, cptr);
    k_fill<<<dim3((unsigned)nb), TPB, 0, stream>>>(m, total, boff, list);
  };
  compact(mask0, 524288, list0, cnt0);
  compact(m1,     65536, list1, cnt1);
  compact(m2,      8192, list2, cnt2);
  compact(m3,      1024, list3, cnt3);

  // subm grids: blocks = max_nq / QPB  (QPB = TPB/(Co/4)); idle blocks exit fast
  const dim3 gL0(4096);   // L0: max nq 131072, QPB 32
  const dim3 gL1(1024);   // L1: max nq 16384,  QPB 16
  const dim3 gL2(256);    // L2: max nq 2048,   QPB 8
  const dim3 gL3(64);     // L3: max nq 256,    QPB 4

  // encoder
  k_subm_t<20, 0, 32, 20, 7, 7, 32><<<gL0, TPB, 0, stream>>>(x, nullptr, w_enc0, bn_enc0, list0, cnt0, zrow, e0);
  k_down_a<32, 64, 6, 6, 16><<<g(65536LL * 16), TPB, 0, stream>>>(e0, w_down0, bn_down0, mask0, list1, cnt1, d0);
  k_subm_t<64, 0, 64, 64, 6, 6, 16><<<gL1, TPB, 0, stream>>>(d0, nullptr, w_enc1, bn_enc1, list1, cnt1, zrow, e1);
  k_down_a<64, 128, 5, 5, 8><<<g(8192LL * 32), TPB, 0, stream>>>(e1, w_down1, bn_down1, m1, list2, cnt2, d1);
  k_subm_t<128, 0, 128, 64, 5, 5, 8><<<gL2, TPB, 0, stream>>>(d1, nullptr, w_enc2, bn_enc2, list2, cnt2, zrow, e2);
  k_down_a<128, 256, 4, 4, 4><<<g(1024LL * 64), TPB, 0, stream>>>(e2, w_down2, bn_down2, m2, list3, cnt3, d2);
  // bottleneck
  k_subm_t<256, 0, 256, 32, 4, 4, 4><<<gL3, TPB, 0, stream>>>(d2, nullptr, w_bott, bn_bott, list3, cnt3, zrow, bb);
  // decoder
  k_up_a<256, 128, 5, 5><<<g(8192LL * 32), TPB, 0, stream>>>(bb, w_up2, list2, cnt2, u2);
  k_subm_t<128, 128, 128, 64, 5, 5, 8><<<gL2, TPB, 0, stream>>>(u2, e2, w_dec2, bn_dec2, list2, cnt2, zrow, c2);
  k_up_a<128, 64, 6, 6><<<g(65536LL * 16), TPB, 0, stream>>>(c2, w_up1, list1, cnt1, u1);
  k_subm_t<64, 64, 64, 64, 6, 6, 16><<<gL1, TPB, 0, stream>>>(u1, e1, w_dec1, bn_dec1, list1, cnt1, zrow, c1);
  k_up_a<64, 32, 7, 7><<<g(524288LL * 8), TPB, 0, stream>>>(c1, w_up0, list0, cnt0, u0);
  k_subm_t<32, 32, 32, 32, 7, 7, 32><<<gL0, TPB, 0, stream>>>(u0, e0, w_dec0, bn_dec0, list0, cnt0, zrow, c0);
  // head
  k_head_a<<<g(524288LL * 45), TPB, 0, stream>>>(c0, w_head, b_head, list0, cnt0, (float*)d_out);
}

// Round 6
// 2388.907 us; speedup vs baseline: 2.7831x; 1.4915x over previous
//
#include <hip/hip_runtime.h>
#include <math.h>

#define TPB 256

// ---------------------------------------------------------------------------
// helpers
// ---------------------------------------------------------------------------
__device__ __forceinline__ float4 ld4(const float* p) { return *(const float4*)p; }

__device__ __forceinline__ void fma4(float s, const float4 w, float4& a) {
  a.x = fmaf(s, w.x, a.x); a.y = fmaf(s, w.y, a.y);
  a.z = fmaf(s, w.z, a.z); a.w = fmaf(s, w.w, a.w);
}

template<int C, int TPV>
__device__ __forceinline__ void dot4(const float* __restrict__ x,
                                     const float4* __restrict__ wp,
                                     float4& acc0, float4& acc1) {
  const float4* __restrict__ xp = (const float4*)x;
  #pragma unroll 8
  for (int c4 = 0; c4 < C / 4; ++c4) {
    const float4 xv = xp[c4];
    fma4(xv.x, wp[(c4 * 4 + 0) * TPV], acc0);
    fma4(xv.y, wp[(c4 * 4 + 1) * TPV], acc1);
    fma4(xv.z, wp[(c4 * 4 + 2) * TPV], acc0);
    fma4(xv.w, wp[(c4 * 4 + 3) * TPV], acc1);
  }
}

// 4 voxels x 4 co over a KC-deep channel chunk; weights from LDS (stride TPV float4)
template<int KC, int TPV>
__device__ __forceinline__ void dot4x4(const float* pa, const float* pb,
                                       const float* pc, const float* pd,
                                       const float4* wp,
                                       float4& A, float4& B, float4& Cc, float4& Dd) {
  const float4* a4 = (const float4*)pa;
  const float4* b4 = (const float4*)pb;
  const float4* c4 = (const float4*)pc;
  const float4* d4 = (const float4*)pd;
  #pragma unroll
  for (int k = 0; k < KC / 4; ++k) {
    const float4 w0 = wp[(k * 4 + 0) * TPV];
    const float4 w1 = wp[(k * 4 + 1) * TPV];
    const float4 w2 = wp[(k * 4 + 2) * TPV];
    const float4 w3 = wp[(k * 4 + 3) * TPV];
    const float4 va = a4[k], vb = b4[k], vc = c4[k], vd = d4[k];
    fma4(va.x, w0, A);  fma4(va.y, w1, A);  fma4(va.z, w2, A);  fma4(va.w, w3, A);
    fma4(vb.x, w0, B);  fma4(vb.y, w1, B);  fma4(vb.z, w2, B);  fma4(vb.w, w3, B);
    fma4(vc.x, w0, Cc); fma4(vc.y, w1, Cc); fma4(vc.z, w2, Cc); fma4(vc.w, w3, Cc);
    fma4(vd.x, w0, Dd); fma4(vd.y, w1, Dd); fma4(vd.z, w2, Dd); fma4(vd.w, w3, Dd);
  }
}

template<int Co>
__device__ __forceinline__ float4 bn_relu(float4 a, const float* __restrict__ bn, int cg) {
  const float4 g = ld4(bn + cg * 4);
  const float4 b = ld4(bn + Co + cg * 4);
  const float4 m = ld4(bn + 2 * Co + cg * 4);
  const float4 v = ld4(bn + 3 * Co + cg * 4);
  float4 r;
  r.x = fmaxf((a.x - m.x) * (g.x * rsqrtf(v.x + 1e-5f)) + b.x, 0.f);
  r.y = fmaxf((a.y - m.y) * (g.y * rsqrtf(v.y + 1e-5f)) + b.y, 0.f);
  r.z = fmaxf((a.z - m.z) * (g.z * rsqrtf(v.z + 1e-5f)) + b.z, 0.f);
  r.w = fmaxf((a.w - m.w) * (g.w * rsqrtf(v.w + 1e-5f)) + b.w, 0.f);
  return r;
}

// ---------------------------------------------------------------------------
// mask pyramid
// ---------------------------------------------------------------------------
template<int LW, int LH, int D>   // coarse dims
__global__ void __launch_bounds__(TPB) k_maskpool(const float* __restrict__ mf,
                                                  float* __restrict__ mc) {
  constexpr int W = 1 << LW, H = 1 << LH;
  constexpr int total = D * H * W;
  const int v = blockIdx.x * TPB + threadIdx.x;
  if (v >= total) return;
  const int w = v & (W - 1), h = (v >> LW) & (H - 1), d = v >> (LW + LH);
  float mp = 0.f;
  #pragma unroll
  for (int dz = 0; dz < 2; ++dz)
    #pragma unroll
    for (int hz = 0; hz < 2; ++hz)
      #pragma unroll
      for (int wz = 0; wz < 2; ++wz)
        mp = fmaxf(mp, mf[((((2*d+dz) << (LH+1)) + (2*h+hz)) << (LW+1)) + (2*w+wz)]);
  mc[v] = mp;
}

// ---------------------------------------------------------------------------
// deterministic ordered compaction: count -> scan -> fill
// ---------------------------------------------------------------------------
__global__ void __launch_bounds__(TPB) k_count(const float* __restrict__ m, int total,
                                               int* __restrict__ bcount) {
  const int v = blockIdx.x * TPB + threadIdx.x;
  const bool act = (v < total) && (m[v] != 0.f);
  const unsigned long long b = __ballot(act);
  __shared__ int wc[TPB / 64];
  const int wid = threadIdx.x >> 6;
  if ((threadIdx.x & 63) == 0) wc[wid] = __popcll(b);
  __syncthreads();
  if (threadIdx.x == 0) bcount[blockIdx.x] = wc[0] + wc[1] + wc[2] + wc[3];
}

__global__ void __launch_bounds__(1024) k_scan(const int* __restrict__ bc, int nb,
                                               int* __restrict__ boff, int* __restrict__ total) {
  __shared__ int part[1024];
  const int t = threadIdx.x;
  const int a0 = (2 * t     < nb) ? bc[2 * t]     : 0;
  const int a1 = (2 * t + 1 < nb) ? bc[2 * t + 1] : 0;
  part[t] = a0 + a1;
  __syncthreads();
  for (int off = 1; off < 1024; off <<= 1) {
    const int tmp = (t >= off) ? part[t - off] : 0;
    __syncthreads();
    part[t] += tmp;
    __syncthreads();
  }
  const int excl = (t == 0) ? 0 : part[t - 1];
  if (2 * t     < nb) boff[2 * t]     = excl;
  if (2 * t + 1 < nb) boff[2 * t + 1] = excl + a0;
  if (t == 1023) *total = part[1023];
}

__global__ void __launch_bounds__(TPB) k_fill(const float* __restrict__ m, int total,
                                              const int* __restrict__ boff,
                                              int* __restrict__ list) {
  const int v = blockIdx.x * TPB + threadIdx.x;
  const bool act = (v < total) && (m[v] != 0.f);
  const unsigned long long b = __ballot(act);
  const int wid = threadIdx.x >> 6, lane = threadIdx.x & 63;
  __shared__ int wc[TPB / 64];
  __shared__ int wbase[TPB / 64];
  if (lane == 0) wc[wid] = __popcll(b);
  __syncthreads();
  if (threadIdx.x == 0) {
    int s = boff[blockIdx.x];
    #pragma unroll
    for (int i = 0; i < TPB / 64; ++i) { wbase[i] = s; s += wc[i]; }
  }
  __syncthreads();
  if (act) {
    const int rank = __popcll(b & ((1ull << lane) - 1ull));
    list[wbase[wid] + rank] = v;
  }
}

// ---------------------------------------------------------------------------
// subm with LDS weight staging (full 27 taps): conv + BN + ReLU
// ---------------------------------------------------------------------------
template<int C1, int C2, int Co, int KC, int LW, int LH, int D>
__global__ void __launch_bounds__(TPB) k_subm_t(
    const float* __restrict__ x1, const float* __restrict__ x2,
    const float* __restrict__ wgt, const float* __restrict__ bn,
    const int* __restrict__ list, const int* __restrict__ cnt,
    const float* __restrict__ zrow, float* __restrict__ out)
{
  constexpr int Cin = C1 + C2;
  constexpr int TPV = Co / 4;
  constexpr int QPB = TPB / TPV;
  constexpr int NCH = Cin / KC;
  constexpr int NW4 = KC * Co / 4;
  constexpr int H = 1 << LH, W = 1 << LW;
  __shared__ float sw[KC * Co];

  const int n = *cnt;
  const int nq = (n + 3) >> 2;
  if ((int)blockIdx.x * QPB >= nq) return;
  const int q  = blockIdx.x * QPB + (int)(threadIdx.x / TPV);
  const int cg = threadIdx.x % TPV;
  const int qc = min(q, nq - 1);

  int vv[4], wx[4], hy[4], dz[4];
  #pragma unroll
  for (int j = 0; j < 4; ++j) {
    const int aa = min(qc * 4 + j, n - 1);
    const int v = list[aa];
    vv[j] = v; wx[j] = v & (W - 1); hy[j] = (v >> LW) & (H - 1); dz[j] = v >> (LW + LH);
  }
  float4 A  = make_float4(0.f, 0.f, 0.f, 0.f);
  float4 B  = make_float4(0.f, 0.f, 0.f, 0.f);
  float4 Cc = make_float4(0.f, 0.f, 0.f, 0.f);
  float4 Dd = make_float4(0.f, 0.f, 0.f, 0.f);

  for (int kd = 0; kd < 3; ++kd)
  for (int kh = 0; kh < 3; ++kh)
  for (int kw = 0; kw < 3; ++kw) {
    const int tap = (kd * 3 + kh) * 3 + kw;
    const float* r1[4];
    const float* r2[4];
    #pragma unroll
    for (int j = 0; j < 4; ++j) {
      const int zd0 = dz[j] + kd - 1, zh0 = hy[j] + kh - 1, zw0 = wx[j] + kw - 1;
      const bool inb = ((unsigned)zd0 < (unsigned)D) &
                       ((unsigned)zh0 < (unsigned)H) &
                       ((unsigned)zw0 < (unsigned)W);
      const int zd = min(max(zd0, 0), D - 1);
      const int zh = min(max(zh0, 0), H - 1);
      const int zw = min(max(zw0, 0), W - 1);
      const int nv = (((zd << LH) + zh) << LW) + zw;
      r1[j] = inb ? x1 + (size_t)nv * C1 : zrow;
      if constexpr (C2 > 0) r2[j] = inb ? x2 + (size_t)nv * C2 : zrow;
    }
    #pragma unroll
    for (int c = 0; c < NCH; ++c) {
      __syncthreads();
      {
        const float4* __restrict__ src =
            (const float4*)(wgt + ((size_t)tap * Cin + c * KC) * Co);
        float4* dst = (float4*)sw;
        #pragma unroll
        for (int t = 0; t < (NW4 + TPB - 1) / TPB; ++t) {
          const int ii = t * TPB + (int)threadIdx.x;
          if (NW4 % TPB == 0 || ii < NW4) dst[ii] = src[ii];
        }
      }
      __syncthreads();
      const float4* wp = (const float4*)sw + cg;
      const int ci0 = c * KC;
      const float *pa, *pb, *pc, *pd;
      if (C2 == 0 || ci0 < C1) {
        pa = r1[0] + ci0; pb = r1[1] + ci0; pc = r1[2] + ci0; pd = r1[3] + ci0;
      } else {
        pa = r2[0] + (ci0 - C1); pb = r2[1] + (ci0 - C1);
        pc = r2[2] + (ci0 - C1); pd = r2[3] + (ci0 - C1);
      }
      dot4x4<KC, TPV>(pa, pb, pc, pd, wp, A, B, Cc, Dd);
    }
  }

  if (q < nq) {
    const int base = qc * 4;
    if (base + 0 < n) *(float4*)(out + (size_t)vv[0] * Co + cg * 4) = bn_relu<Co>(A,  bn, cg);
    if (base + 1 < n) *(float4*)(out + (size_t)vv[1] * Co + cg * 4) = bn_relu<Co>(B,  bn, cg);
    if (base + 2 < n) *(float4*)(out + (size_t)vv[2] * Co + cg * 4) = bn_relu<Co>(Cc, bn, cg);
    if (base + 3 < n) *(float4*)(out + (size_t)vv[3] * Co + cg * 4) = bn_relu<Co>(Dd, bn, cg);
  }
}

// ---------------------------------------------------------------------------
// subm TAP-SPLIT: blockIdx.y = split s handles taps [s*TPS, (s+1)*TPS);
// writes RAW partial sums (no BN) to pbuf[s][a][Co], a = list position.
// Reduce kernel sums splits in fixed order -> deterministic.
// ---------------------------------------------------------------------------
template<int C1, int C2, int Co, int KC, int LW, int LH, int D, int NSPLIT, int CAP>
__global__ void __launch_bounds__(TPB) k_subm_p(
    const float* __restrict__ x1, const float* __restrict__ x2,
    const float* __restrict__ wgt,
    const int* __restrict__ list, const int* __restrict__ cnt,
    const float* __restrict__ zrow, float* __restrict__ pbuf)
{
  constexpr int Cin = C1 + C2;
  constexpr int TPV = Co / 4;
  constexpr int QPB = TPB / TPV;
  constexpr int NCH = Cin / KC;
  constexpr int NW4 = KC * Co / 4;
  constexpr int TPS = 27 / NSPLIT;
  constexpr int H = 1 << LH, W = 1 << LW;
  __shared__ float sw[KC * Co];

  const int n = *cnt;
  const int nq = (n + 3) >> 2;
  if ((int)blockIdx.x * QPB >= nq) return;
  const int s  = blockIdx.y;
  const int q  = blockIdx.x * QPB + (int)(threadIdx.x / TPV);
  const int cg = threadIdx.x % TPV;
  const int qc = min(q, nq - 1);

  int wx[4], hy[4], dz[4];
  #pragma unroll
  for (int j = 0; j < 4; ++j) {
    const int aa = min(qc * 4 + j, n - 1);
    const int v = list[aa];
    wx[j] = v & (W - 1); hy[j] = (v >> LW) & (H - 1); dz[j] = v >> (LW + LH);
  }
  float4 A  = make_float4(0.f, 0.f, 0.f, 0.f);
  float4 B  = make_float4(0.f, 0.f, 0.f, 0.f);
  float4 Cc = make_float4(0.f, 0.f, 0.f, 0.f);
  float4 Dd = make_float4(0.f, 0.f, 0.f, 0.f);

  for (int t = s * TPS; t < (s + 1) * TPS; ++t) {
    const int kd = t / 9, kh = (t / 3) % 3, kw = t % 3;
    const float* r1[4];
    const float* r2[4];
    #pragma unroll
    for (int j = 0; j < 4; ++j) {
      const int zd0 = dz[j] + kd - 1, zh0 = hy[j] + kh - 1, zw0 = wx[j] + kw - 1;
      const bool inb = ((unsigned)zd0 < (unsigned)D) &
                       ((unsigned)zh0 < (unsigned)H) &
                       ((unsigned)zw0 < (unsigned)W);
      const int zd = min(max(zd0, 0), D - 1);
      const int zh = min(max(zh0, 0), H - 1);
      const int zw = min(max(zw0, 0), W - 1);
      const int nv = (((zd << LH) + zh) << LW) + zw;
      r1[j] = inb ? x1 + (size_t)nv * C1 : zrow;
      if constexpr (C2 > 0) r2[j] = inb ? x2 + (size_t)nv * C2 : zrow;
    }
    #pragma unroll
    for (int c = 0; c < NCH; ++c) {
      __syncthreads();
      {
        const float4* __restrict__ src =
            (const float4*)(wgt + ((size_t)t * Cin + c * KC) * Co);
        float4* dst = (float4*)sw;
        #pragma unroll
        for (int tt = 0; tt < (NW4 + TPB - 1) / TPB; ++tt) {
          const int ii = tt * TPB + (int)threadIdx.x;
          if (NW4 % TPB == 0 || ii < NW4) dst[ii] = src[ii];
        }
      }
      __syncthreads();
      const float4* wp = (const float4*)sw + cg;
      const int ci0 = c * KC;
      const float *pa, *pb, *pc, *pd;
      if (C2 == 0 || ci0 < C1) {
        pa = r1[0] + ci0; pb = r1[1] + ci0; pc = r1[2] + ci0; pd = r1[3] + ci0;
      } else {
        pa = r2[0] + (ci0 - C1); pb = r2[1] + (ci0 - C1);
        pc = r2[2] + (ci0 - C1); pd = r2[3] + (ci0 - C1);
      }
      dot4x4<KC, TPV>(pa, pb, pc, pd, wp, A, B, Cc, Dd);
    }
  }

  if (q < nq) {
    float* base = pbuf + ((size_t)s * CAP + (size_t)qc * 4) * Co + cg * 4;
    const int b0 = qc * 4;
    if (b0 + 0 < n) *(float4*)(base + 0 * Co) = A;
    if (b0 + 1 < n) *(float4*)(base + 1 * Co) = B;
    if (b0 + 2 < n) *(float4*)(base + 2 * Co) = Cc;
    if (b0 + 3 < n) *(float4*)(base + 3 * Co) = Dd;
  }
}

// sum NSPLIT partials in fixed order + BN + ReLU + scatter to out[v]
template<int Co, int NSPLIT, int CAP>
__global__ void __launch_bounds__(TPB) k_reduce_bn(
    const float* __restrict__ pbuf, const float* __restrict__ bn,
    const int* __restrict__ list, const int* __restrict__ cnt,
    float* __restrict__ out)
{
  constexpr int TPV = Co / 4;
  const int n = *cnt;
  const int total = n * TPV;
  for (int i = blockIdx.x * TPB + threadIdx.x; i < total; i += gridDim.x * TPB) {
    const int a = i / TPV;
    const int cg = i % TPV;
    float4 acc = make_float4(0.f, 0.f, 0.f, 0.f);
    #pragma unroll
    for (int s = 0; s < NSPLIT; ++s) {
      const float4 p = ld4(pbuf + ((size_t)s * CAP + a) * Co + cg * 4);
      acc.x += p.x; acc.y += p.y; acc.z += p.z; acc.w += p.w;
    }
    const int v = list[a];
    *(float4*)(out + (size_t)v * Co + cg * 4) = bn_relu<Co>(acc, bn, cg);
  }
}

// ---------------------------------------------------------------------------
// down over coarse active list (2x2x2 stride-2 + BN + ReLU, fine-mask skip)
// ---------------------------------------------------------------------------
template<int Ci, int Co, int LW, int LH, int D>
__global__ void __launch_bounds__(TPB) k_down_a(
    const float* __restrict__ x, const float* __restrict__ wgt,
    const float* __restrict__ bn, const float* __restrict__ mfine,
    const int* __restrict__ list, const int* __restrict__ cnt,
    float* __restrict__ out)
{
  constexpr int TPV = Co / 4;
  constexpr int H = 1 << LH, W = 1 << LW;
  const int n = *cnt;
  const int total = n * TPV;
  for (int i = blockIdx.x * TPB + threadIdx.x; i < total; i += gridDim.x * TPB) {
    const int a = i / TPV;
    const int cg = i % TPV;
    const int v = list[a];
    const int w = v & (W - 1), h = (v >> LW) & (H - 1), d = v >> (LW + LH);
    float4 acc0 = make_float4(0.f, 0.f, 0.f, 0.f);
    float4 acc1 = make_float4(0.f, 0.f, 0.f, 0.f);
    #pragma unroll
    for (int kd = 0; kd < 2; ++kd)
      #pragma unroll
      for (int kh = 0; kh < 2; ++kh)
        #pragma unroll
        for (int kw = 0; kw < 2; ++kw) {
          const int nv = ((((2*d+kd) << (LH+1)) + (2*h+kh)) << (LW+1)) + (2*w+kw);
          if (mfine[nv] == 0.f) continue;
          const int tap = (kd * 2 + kh) * 2 + kw;
          const float4* __restrict__ wp = (const float4*)wgt + (size_t)tap * Ci * TPV + cg;
          dot4<Ci, TPV>(x + (size_t)nv * Ci, wp, acc0, acc1);
        }
    float4 acc;
    acc.x = acc0.x + acc1.x; acc.y = acc0.y + acc1.y;
    acc.z = acc0.z + acc1.z; acc.w = acc0.w + acc1.w;
    *(float4*)(out + (size_t)v * Co + cg * 4) = bn_relu<Co>(acc, bn, cg);
  }
}

// ---------------------------------------------------------------------------
// up over FINE active list: 1-tap conv_transpose
// ---------------------------------------------------------------------------
template<int Ci, int Co, int LW, int LH>
__global__ void __launch_bounds__(TPB) k_up_a(
    const float* __restrict__ x, const float* __restrict__ wgt,
    const int* __restrict__ list, const int* __restrict__ cnt,
    float* __restrict__ out)
{
  constexpr int TPV = Co / 4;
  constexpr int H = 1 << LH, W = 1 << LW;
  const int n = *cnt;
  const int total = n * TPV;
  for (int i = blockIdx.x * TPB + threadIdx.x; i < total; i += gridDim.x * TPB) {
    const int a = i / TPV;
    const int cg = i % TPV;
    const int v = list[a];
    const int w = v & (W - 1), h = (v >> LW) & (H - 1), d = v >> (LW + LH);
    const int kd = 1 - (d & 1), kh = 1 - (h & 1), kw = 1 - (w & 1);
    const int nv = ((((d >> 1) << (LH - 1)) + (h >> 1)) << (LW - 1)) + (w >> 1);
    const int tap = (kd * 2 + kh) * 2 + kw;
    const float4* __restrict__ wp = (const float4*)wgt + (size_t)tap * Ci * TPV + cg;
    float4 acc0 = make_float4(0.f, 0.f, 0.f, 0.f);
    float4 acc1 = make_float4(0.f, 0.f, 0.f, 0.f);
    dot4<Ci, TPV>(x + (size_t)nv * Ci, wp, acc0, acc1);
    float4 acc;
    acc.x = acc0.x + acc1.x; acc.y = acc0.y + acc1.y;
    acc.z = acc0.z + acc1.z; acc.w = acc0.w + acc1.w;
    *(float4*)(out + (size_t)v * Co + cg * 4) = acc;
  }
}

// ---------------------------------------------------------------------------
// head over active list
// ---------------------------------------------------------------------------
__global__ void __launch_bounds__(TPB) k_head_a(
    const float* __restrict__ c0, const float* __restrict__ wh,
    const float* __restrict__ bh, const int* __restrict__ list,
    const int* __restrict__ cnt, float* __restrict__ out)
{
  __shared__ float sw[32 * 45];
  __shared__ float sb[45];
  for (int t = threadIdx.x; t < 32 * 45; t += TPB) sw[t] = wh[t];
  if (threadIdx.x < 45) sb[threadIdx.x] = bh[threadIdx.x];
  __syncthreads();
  const int n = *cnt;
  const int total = n * 45;
  const size_t NV = 524288;
  for (int i = blockIdx.x * TPB + threadIdx.x; i < total; i += gridDim.x * TPB) {
    const int a = i / 45;
    const int j = i % 45;
    const int v = list[a];
    const float4* __restrict__ cp = (const float4*)(c0 + (size_t)v * 32);
    float a0 = 0.f, a1 = 0.f;
    #pragma unroll
    for (int c4 = 0; c4 < 8; ++c4) {
      const float4 xv = cp[c4];
      a0 = fmaf(xv.x, sw[(c4 * 4 + 0) * 45 + j], a0);
      a1 = fmaf(xv.y, sw[(c4 * 4 + 1) * 45 + j], a1);
      a0 = fmaf(xv.z, sw[(c4 * 4 + 2) * 45 + j], a0);
      a1 = fmaf(xv.w, sw[(c4 * 4 + 3) * 45 + j], a1);
    }
    const float val = a0 + a1 + sb[j];
    const int k = j / 9, r = j % 9;
    if (r < 3)
      out[(size_t)v * 15 + k * 3 + r] = val;
    else if (r < 6)
      out[NV * 15 + (size_t)v * 15 + k * 3 + (r - 3)] = fminf(fmaxf(val, -5.f), 3.f);
    else if (r == 6)
      out[NV * 30 + (size_t)v * 5 + k] = val;
    else if (r == 7)
      out[NV * 35 + (size_t)v * 5 + k] = val;
    else
      out[NV * 40 + (size_t)v * 5 + k] = val;
  }
}

// ---------------------------------------------------------------------------
extern "C" void kernel_launch(void* const* d_in, const int* in_sizes, int n_in,
                              void* d_out, int out_size, void* d_ws, size_t ws_size,
                              hipStream_t stream)
{
  (void)in_sizes; (void)n_in;

  const float* x        = (const float*)d_in[0];
  const float* mask0    = (const float*)d_in[1];
  const float* w_enc0   = (const float*)d_in[2];
  const float* bn_enc0  = (const float*)d_in[3];
  const float* w_down0  = (const float*)d_in[4];
  const float* bn_down0 = (const float*)d_in[5];
  const float* w_enc1   = (const float*)d_in[6];
  const float* bn_enc1  = (const float*)d_in[7];
  const float* w_down1  = (const float*)d_in[8];
  const float* bn_down1 = (const float*)d_in[9];
  const float* w_enc2   = (const float*)d_in[10];
  const float* bn_enc2  = (const float*)d_in[11];
  const float* w_down2  = (const float*)d_in[12];
  const float* bn_down2 = (const float*)d_in[13];
  const float* w_bott   = (const float*)d_in[14];
  const float* bn_bott  = (const float*)d_in[15];
  const float* w_up2    = (const float*)d_in[16];
  const float* w_dec2   = (const float*)d_in[17];
  const float* bn_dec2  = (const float*)d_in[18];
  const float* w_up1    = (const float*)d_in[19];
  const float* w_dec1   = (const float*)d_in[20];
  const float* bn_dec1  = (const float*)d_in[21];
  const float* w_up0    = (const float*)d_in[22];
  const float* w_dec0   = (const float*)d_in[23];
  const float* bn_dec0  = (const float*)d_in[24];
  const float* w_head   = (const float*)d_in[25];
  const float* b_head   = (const float*)d_in[26];

  float* ws = (float*)d_ws;
  size_t o = 0;
  auto take = [&](size_t nf) { float* p = ws + o; o += nf; return p; };

  int*   cnt   = (int*)take(16);
  int*   bcnt  = (int*)take(2048);
  int*   boff  = (int*)take(2048);
  int*   list0 = (int*)take(524288);
  int*   list1 = (int*)take(65536);
  int*   list2 = (int*)take(8192);
  int*   list3 = (int*)take(1024);
  float* zrow  = take(256);
  float* m1    = take(65536);
  float* m2    = take(8192);
  float* m3    = take(1024);
  float* e0 = take(16777216);
  float* d0 = take(4194304);              // reused as u1
  float* e1 = take(4194304);
  float* d1 = take(1048576);              // reused as u2
  float* e2 = take(1048576);
  float* d2 = take(262144);
  float* bb = take(262144);
  float* c2 = take(1048576);
  float* c1 = take(4194304);
  float* u0 = take(16777216);
  float* c0 = take(16777216);
  if (o * sizeof(float) > ws_size) return;
  float* u2 = d1;
  float* u1 = d0;
  float* pbuf = c0;   // partials for deep layers live in c0's region (c0 written later)
  int* cnt0 = cnt, *cnt1 = cnt + 1, *cnt2 = cnt + 2, *cnt3 = cnt + 3;

  // zero output + gathered buffers (inactive rows must read as 0)
  hipMemsetAsync(d_out, 0, (size_t)out_size * sizeof(float), stream);
  hipMemsetAsync(zrow, 0, 256 * sizeof(float), stream);
  hipMemsetAsync(e0, 0, 16777216 * sizeof(float), stream);
  hipMemsetAsync(d0, 0, 4194304 * sizeof(float), stream);
  hipMemsetAsync(e1, 0, 4194304 * sizeof(float), stream);
  hipMemsetAsync(d1, 0, 1048576 * sizeof(float), stream);
  hipMemsetAsync(e2, 0, 1048576 * sizeof(float), stream);
  hipMemsetAsync(d2, 0, 262144 * sizeof(float), stream);
  hipMemsetAsync(u0, 0, 16777216 * sizeof(float), stream);

  auto g = [](long long upper) {
    unsigned b = (unsigned)((upper + TPB - 1) / TPB);
    return dim3(b > 4096u ? 4096u : (b ? b : 1u));
  };

  // mask pyramid
  k_maskpool<6, 6, 16><<<g(65536), TPB, 0, stream>>>(mask0, m1);
  k_maskpool<5, 5, 8><<<g(8192), TPB, 0, stream>>>(m1, m2);
  k_maskpool<4, 4, 4><<<g(1024), TPB, 0, stream>>>(m2, m3);

  // deterministic ordered compaction per level
  auto compact = [&](const float* m, int total, int* list, int* cptr) {
    const int nb = total / TPB;
    k_count<<<dim3((unsigned)nb), TPB, 0, stream>>>(m, total, bcnt);
    k_scan<<<dim3(1), 1024, 0, stream>>>(bcnt, nb, boff, cptr);
    k_fill<<<dim3((unsigned)nb), TPB, 0, stream>>>(m, total, boff, list);
  };
  compact(mask0, 524288, list0, cnt0);
  compact(m1,     65536, list1, cnt1);
  compact(m2,      8192, list2, cnt2);
  compact(m3,      1024, list3, cnt3);

  // subm grids (x = max quads / QPB; idle blocks exit fast)
  const dim3 gL0(4096);   // L0: max nq 131072, QPB 32
  const dim3 gL1(1024);   // L1: max nq 16384,  QPB 16

  // encoder
  k_subm_t<20, 0, 32, 20, 7, 7, 32><<<gL0, TPB, 0, stream>>>(x, nullptr, w_enc0, bn_enc0, list0, cnt0, zrow, e0);
  k_down_a<32, 64, 6, 6, 16><<<g(65536LL * 16), TPB, 0, stream>>>(e0, w_down0, bn_down0, mask0, list1, cnt1, d0);
  k_subm_t<64, 0, 64, 64, 6, 6, 16><<<gL1, TPB, 0, stream>>>(d0, nullptr, w_enc1, bn_enc1, list1, cnt1, zrow, e1);
  k_down_a<64, 128, 5, 5, 8><<<g(8192LL * 32), TPB, 0, stream>>>(e1, w_down1, bn_down1, m1, list2, cnt2, d1);
  // enc2: tap-split x3
  k_subm_p<128, 0, 128, 64, 5, 5, 8, 3, 8192><<<dim3(256, 3), TPB, 0, stream>>>(d1, nullptr, w_enc2, list2, cnt2, zrow, pbuf);
  k_reduce_bn<128, 3, 8192><<<g(8192LL * 32), TPB, 0, stream>>>(pbuf, bn_enc2, list2, cnt2, e2);
  k_down_a<128, 256, 4, 4, 4><<<g(1024LL * 64), TPB, 0, stream>>>(e2, w_down2, bn_down2, m2, list3, cnt3, d2);
  // bottleneck: tap-split x9
  k_subm_p<256, 0, 256, 32, 4, 4, 4, 9, 1024><<<dim3(64, 9), TPB, 0, stream>>>(d2, nullptr, w_bott, list3, cnt3, zrow, pbuf);
  k_reduce_bn<256, 9, 1024><<<g(1024LL * 64), TPB, 0, stream>>>(pbuf, bn_bott, list3, cnt3, bb);
  // decoder
  k_up_a<256, 128, 5, 5><<<g(8192LL * 32), TPB, 0, stream>>>(bb, w_up2, list2, cnt2, u2);
  // dec2: tap-split x3 (concat u2|e2)
  k_subm_p<128, 128, 128, 64, 5, 5, 8, 3, 8192><<<dim3(256, 3), TPB, 0, stream>>>(u2, e2, w_dec2, list2, cnt2, zrow, pbuf);
  k_reduce_bn<128, 3, 8192><<<g(8192LL * 32), TPB, 0, stream>>>(pbuf, bn_dec2, list2, cnt2, c2);
  k_up_a<128, 64, 6, 6><<<g(65536LL * 16), TPB, 0, stream>>>(c2, w_up1, list1, cnt1, u1);
  k_subm_t<64, 64, 64, 64, 6, 6, 16><<<gL1, TPB, 0, stream>>>(u1, e1, w_dec1, bn_dec1, list1, cnt1, zrow, c1);
  k_up_a<64, 32, 7, 7><<<g(524288LL * 8), TPB, 0, stream>>>(c1, w_up0, list0, cnt0, u0);
  k_subm_t<32, 32, 32, 32, 7, 7, 32><<<gL0, TPB, 0, stream>>>(u0, e0, w_dec0, bn_dec0, list0, cnt0, zrow, c0);
  // head
  k_head_a<<<g(524288LL * 45), TPB, 0, stream>>>(c0, w_head, b_head, list0, cnt0, (float*)d_out);
}

// Round 7
// 1289.204 us; speedup vs baseline: 5.1572x; 1.8530x over previous
//
#include <hip/hip_runtime.h>
#include <math.h>

#define TPB 256

typedef __attribute__((ext_vector_type(8))) short short8v;
typedef __attribute__((ext_vector_type(4))) short short4v;
typedef __attribute__((ext_vector_type(4))) float f32x4;

// ---------------------------------------------------------------------------
// bf16 helpers
// ---------------------------------------------------------------------------
__device__ __forceinline__ float b2f(unsigned short u) {
  union { unsigned i; float f; } x; x.i = ((unsigned)u) << 16; return x.f;
}
__device__ __forceinline__ unsigned short f2b(float f) {
  union { float f; unsigned i; } x; x.f = f;
  unsigned r = (x.i + 0x7fffu + ((x.i >> 16) & 1u)) >> 16;
  return (unsigned short)r;
}

__device__ __forceinline__ float4 ld4(const float* p) { return *(const float4*)p; }

__device__ __forceinline__ void fma4(float s, const float4 w, float4& a) {
  a.x = fmaf(s, w.x, a.x); a.y = fmaf(s, w.y, a.y);
  a.z = fmaf(s, w.z, a.z); a.w = fmaf(s, w.w, a.w);
}

template<int Co>
__device__ __forceinline__ float4 bn_relu4(float4 a, const float* __restrict__ bn, int cg) {
  const float4 g = ld4(bn + cg * 4);
  const float4 b = ld4(bn + Co + cg * 4);
  const float4 m = ld4(bn + 2 * Co + cg * 4);
  const float4 v = ld4(bn + 3 * Co + cg * 4);
  float4 r;
  r.x = fmaxf((a.x - m.x) * (g.x * rsqrtf(v.x + 1e-5f)) + b.x, 0.f);
  r.y = fmaxf((a.y - m.y) * (g.y * rsqrtf(v.y + 1e-5f)) + b.y, 0.f);
  r.z = fmaxf((a.z - m.z) * (g.z * rsqrtf(v.z + 1e-5f)) + b.z, 0.f);
  r.w = fmaxf((a.w - m.w) * (g.w * rsqrtf(v.w + 1e-5f)) + b.w, 0.f);
  return r;
}

// ---------------------------------------------------------------------------
// mask pyramid (fp32 masks)
// ---------------------------------------------------------------------------
template<int LW, int LH, int D>
__global__ void __launch_bounds__(TPB) k_maskpool(const float* __restrict__ mf,
                                                  float* __restrict__ mc) {
  constexpr int W = 1 << LW, H = 1 << LH;
  constexpr int total = D * H * W;
  const int v = blockIdx.x * TPB + threadIdx.x;
  if (v >= total) return;
  const int w = v & (W - 1), h = (v >> LW) & (H - 1), d = v >> (LW + LH);
  float mp = 0.f;
  #pragma unroll
  for (int dz = 0; dz < 2; ++dz)
    #pragma unroll
    for (int hz = 0; hz < 2; ++hz)
      #pragma unroll
      for (int wz = 0; wz < 2; ++wz)
        mp = fmaxf(mp, mf[((((2*d+dz) << (LH+1)) + (2*h+hz)) << (LW+1)) + (2*w+wz)]);
  mc[v] = mp;
}

// ---------------------------------------------------------------------------
// deterministic ordered compaction: count -> scan -> fill
// ---------------------------------------------------------------------------
__global__ void __launch_bounds__(TPB) k_count(const float* __restrict__ m, int total,
                                               int* __restrict__ bcount) {
  const int v = blockIdx.x * TPB + threadIdx.x;
  const bool act = (v < total) && (m[v] != 0.f);
  const unsigned long long b = __ballot(act);
  __shared__ int wc[TPB / 64];
  const int wid = threadIdx.x >> 6;
  if ((threadIdx.x & 63) == 0) wc[wid] = __popcll(b);
  __syncthreads();
  if (threadIdx.x == 0) bcount[blockIdx.x] = wc[0] + wc[1] + wc[2] + wc[3];
}

__global__ void __launch_bounds__(1024) k_scan(const int* __restrict__ bc, int nb,
                                               int* __restrict__ boff, int* __restrict__ total) {
  __shared__ int part[1024];
  const int t = threadIdx.x;
  const int a0 = (2 * t     < nb) ? bc[2 * t]     : 0;
  const int a1 = (2 * t + 1 < nb) ? bc[2 * t + 1] : 0;
  part[t] = a0 + a1;
  __syncthreads();
  for (int off = 1; off < 1024; off <<= 1) {
    const int tmp = (t >= off) ? part[t - off] : 0;
    __syncthreads();
    part[t] += tmp;
    __syncthreads();
  }
  const int excl = (t == 0) ? 0 : part[t - 1];
  if (2 * t     < nb) boff[2 * t]     = excl;
  if (2 * t + 1 < nb) boff[2 * t + 1] = excl + a0;
  if (t == 1023) *total = part[1023];
}

__global__ void __launch_bounds__(TPB) k_fill(const float* __restrict__ m, int total,
                                              const int* __restrict__ boff,
                                              int* __restrict__ list) {
  const int v = blockIdx.x * TPB + threadIdx.x;
  const bool act = (v < total) && (m[v] != 0.f);
  const unsigned long long b = __ballot(act);
  const int wid = threadIdx.x >> 6, lane = threadIdx.x & 63;
  __shared__ int wc[TPB / 64];
  __shared__ int wbase[TPB / 64];
  if (lane == 0) wc[wid] = __popcll(b);
  __syncthreads();
  if (threadIdx.x == 0) {
    int s = boff[blockIdx.x];
    #pragma unroll
    for (int i = 0; i < TPB / 64; ++i) { wbase[i] = s; s += wc[i]; }
  }
  __syncthreads();
  if (act) {
    const int rank = __popcll(b & ((1ull << lane) - 1ull));
    list[wbase[wid] + rank] = v;
  }
}

// ---------------------------------------------------------------------------
// x: fp32 [NV][20] -> bf16 [NV][32] (zero-padded channels)
// ---------------------------------------------------------------------------
__global__ void __launch_bounds__(TPB) k_cvtx(const float* __restrict__ x,
                                              unsigned short* __restrict__ xb, int NV) {
  const int v = blockIdx.x * TPB + threadIdx.x;
  if (v >= NV) return;
  const float* r = x + (size_t)v * 20;
  unsigned short* o = xb + (size_t)v * 32;
  #pragma unroll
  for (int c4 = 0; c4 < 5; ++c4) {
    const float4 f = ld4(r + c4 * 4);
    short4v s; s[0] = (short)f2b(f.x); s[1] = (short)f2b(f.y);
    s[2] = (short)f2b(f.z); s[3] = (short)f2b(f.w);
    *(short4v*)(o + c4 * 4) = s;
  }
  const short4v z = {0, 0, 0, 0};
  *(short4v*)(o + 20) = z; *(short4v*)(o + 24) = z; *(short4v*)(o + 28) = z;
}

// ---------------------------------------------------------------------------
// weight pack: fp32 [27][C1r+C2][Co] -> bf16 MFMA-B fragments.
// pw[(((t*NT+nt)*NKC+kc)*64 + l)*8 + j] = W[t][k][n], k=kc*32+(l>>4)*8+j (padded),
// n=nt*16+(l&15).  Padded K-space: [0,C1p) from input1 (zeros past C1r), then C2.
// ---------------------------------------------------------------------------
template<int C1r, int C1p, int C2, int Co>
__global__ void __launch_bounds__(TPB) k_packw(const float* __restrict__ w,
                                               unsigned short* __restrict__ pw) {
  constexpr int NT = Co / 16;
  constexpr int NKC = (C1p + C2) / 32;
  constexpr int total = 27 * NT * NKC * 512;
  const int idx = blockIdx.x * TPB + threadIdx.x;
  if (idx >= total) return;
  const int j = idx & 7;
  const int l = (idx >> 3) & 63;
  int rest = idx >> 9;
  const int kc = rest % NKC; rest /= NKC;
  const int nt = rest % NT;
  const int t = rest / NT;
  const int k = kc * 32 + ((l >> 4) << 3) + j;
  const int n = nt * 16 + (l & 15);
  int ksrc;
  if (k < C1p) ksrc = (k < C1r) ? k : -1;
  else         ksrc = C1r + (k - C1p);
  const float val = (ksrc < 0) ? 0.f : w[((size_t)t * (C1r + C2) + ksrc) * Co + n];
  pw[idx] = f2b(val);
}

// ---------------------------------------------------------------------------
// subm via MFMA: 3x3x3 SAME conv (+concat) + BN + ReLU, bf16 in/out, fp32 accum.
// Wave = 32 voxels x 16 co-tile(s). A gathered per tap/lane; B from packed pw.
// A layout: lane l -> row l&15, k=(l>>4)*8+j.  D: col=l&15, row=(l>>4)*4+i.
// ---------------------------------------------------------------------------
template<int C1p, int C2, int Co, int LW, int LH, int D>
__global__ void __launch_bounds__(TPB) k_subm_m(
    const unsigned short* __restrict__ xb1, const unsigned short* __restrict__ xb2,
    const unsigned short* __restrict__ pw, const float* __restrict__ bn,
    const int* __restrict__ list, const int* __restrict__ cnt,
    const unsigned short* __restrict__ zb, unsigned short* __restrict__ out)
{
  constexpr int NT = Co / 16;
  constexpr int NKC1 = C1p / 32;
  constexpr int NKC = (C1p + C2) / 32;
  constexpr int MH = (NT >= 4) ? 1 : 2;          // m-halves per block
  constexpr int NTPW = (NT >= 4) ? NT / 4 : 1;   // n-tiles per wave
  constexpr int MVB = 32 * MH;                   // voxels per block
  constexpr int H = 1 << LH, W = 1 << LW;

  const int n = *cnt;
  if (n == 0) return;
  const int nmt = (n + MVB - 1) / MVB;
  const int wv = threadIdx.x >> 6, l = threadIdx.x & 63;
  const int mhalf = (MH == 2) ? (wv >> 1) : 0;
  const int nt0   = (MH == 2) ? (wv & 1) : wv * NTPW;
  const int lm = l & 15, lg = l >> 4;

  for (int mt = blockIdx.x; mt < nmt; mt += gridDim.x) {
    const int r0 = mt * MVB + mhalf * 32;
    int wx[2], hy[2], dzz[2];
    #pragma unroll
    for (int h2 = 0; h2 < 2; ++h2) {
      const int g = min(r0 + h2 * 16 + lm, n - 1);
      const int v = list[g];
      wx[h2] = v & (W - 1); hy[h2] = (v >> LW) & (H - 1); dzz[h2] = v >> (LW + LH);
    }
    f32x4 acc[NTPW][2];
    #pragma unroll
    for (int q = 0; q < NTPW; ++q)
      #pragma unroll
      for (int h2 = 0; h2 < 2; ++h2)
        acc[q][h2] = (f32x4){0.f, 0.f, 0.f, 0.f};

    for (int t = 0; t < 27; ++t) {
      const int kd = t / 9, kh = (t / 3) % 3, kw = t % 3;
      const unsigned short* p1[2];
      const unsigned short* p2[2];
      #pragma unroll
      for (int h2 = 0; h2 < 2; ++h2) {
        const int zd0 = dzz[h2] + kd - 1, zh0 = hy[h2] + kh - 1, zw0 = wx[h2] + kw - 1;
        const bool inb = ((unsigned)zd0 < (unsigned)D) &
                         ((unsigned)zh0 < (unsigned)H) &
                         ((unsigned)zw0 < (unsigned)W);
        const int zd = min(max(zd0, 0), D - 1);
        const int zh = min(max(zh0, 0), H - 1);
        const int zw = min(max(zw0, 0), W - 1);
        const int nv = (((zd << LH) + zh) << LW) + zw;
        p1[h2] = (inb ? xb1 + (size_t)nv * C1p : zb) + lg * 8;
        if constexpr (C2 > 0) p2[h2] = (inb ? xb2 + (size_t)nv * C2 : zb) + lg * 8;
      }
      #pragma unroll
      for (int kc = 0; kc < NKC; ++kc) {
        short8v a0, a1;
        if (C2 == 0 || kc < NKC1) {
          const int coff = kc * 32;
          a0 = *(const short8v*)(p1[0] + coff);
          a1 = *(const short8v*)(p1[1] + coff);
        } else {
          const int coff = (kc - NKC1) * 32;
          a0 = *(const short8v*)(p2[0] + coff);
          a1 = *(const short8v*)(p2[1] + coff);
        }
        #pragma unroll
        for (int q = 0; q < NTPW; ++q) {
          const int nt = nt0 + q;
          const short8v b = *(const short8v*)(pw + ((((size_t)t * NT + nt) * NKC + kc) << 9) + l * 8);
          acc[q][0] = __builtin_amdgcn_mfma_f32_16x16x32_bf16(a0, b, acc[q][0], 0, 0, 0);
          acc[q][1] = __builtin_amdgcn_mfma_f32_16x16x32_bf16(a1, b, acc[q][1], 0, 0, 0);
        }
      }
    }
    // epilogue: D col = lm, row = lg*4 + i
    #pragma unroll
    for (int q = 0; q < NTPW; ++q) {
      const int nt = nt0 + q;
      const int co = nt * 16 + lm;
      const float sc = bn[co] * rsqrtf(bn[3 * Co + co] + 1e-5f);
      const float sh = bn[Co + co] - bn[2 * Co + co] * sc;
      #pragma unroll
      for (int h2 = 0; h2 < 2; ++h2)
        #pragma unroll
        for (int i = 0; i < 4; ++i) {
          const int g = r0 + h2 * 16 + lg * 4 + i;
          if (g < n) {
            const int v = list[g];
            const float y = fmaxf(acc[q][h2][i] * sc + sh, 0.f);
            out[(size_t)v * Co + co] = f2b(y);
          }
        }
    }
  }
}

// ---------------------------------------------------------------------------
// down: 2x2x2 stride-2 conv + BN + ReLU; bf16 acts, fp32 weights/math
// ---------------------------------------------------------------------------
template<int Ci, int Co, int LW, int LH, int D>
__global__ void __launch_bounds__(TPB) k_down_b(
    const unsigned short* __restrict__ x, const float* __restrict__ wgt,
    const float* __restrict__ bn, const float* __restrict__ mfine,
    const int* __restrict__ list, const int* __restrict__ cnt,
    unsigned short* __restrict__ out)
{
  constexpr int TPV = Co / 4;
  constexpr int H = 1 << LH, W = 1 << LW;
  const int n = *cnt;
  const int total = n * TPV;
  for (int i = blockIdx.x * TPB + threadIdx.x; i < total; i += gridDim.x * TPB) {
    const int a = i / TPV;
    const int cg = i % TPV;
    const int v = list[a];
    const int w = v & (W - 1), h = (v >> LW) & (H - 1), d = v >> (LW + LH);
    float4 acc0 = make_float4(0.f, 0.f, 0.f, 0.f);
    float4 acc1 = make_float4(0.f, 0.f, 0.f, 0.f);
    #pragma unroll
    for (int kd = 0; kd < 2; ++kd)
      #pragma unroll
      for (int kh = 0; kh < 2; ++kh)
        #pragma unroll
        for (int kw = 0; kw < 2; ++kw) {
          const int nv = ((((2*d+kd) << (LH+1)) + (2*h+kh)) << (LW+1)) + (2*w+kw);
          if (mfine[nv] == 0.f) continue;
          const int tap = (kd * 2 + kh) * 2 + kw;
          const float4* __restrict__ wp = (const float4*)wgt + (size_t)tap * Ci * TPV + cg;
          const unsigned short* row = x + (size_t)nv * Ci;
          #pragma unroll
          for (int c8 = 0; c8 < Ci / 8; ++c8) {
            const short8v s = *(const short8v*)(row + c8 * 8);
            fma4(b2f((unsigned short)s[0]), wp[(c8 * 8 + 0) * TPV], acc0);
            fma4(b2f((unsigned short)s[1]), wp[(c8 * 8 + 1) * TPV], acc1);
            fma4(b2f((unsigned short)s[2]), wp[(c8 * 8 + 2) * TPV], acc0);
            fma4(b2f((unsigned short)s[3]), wp[(c8 * 8 + 3) * TPV], acc1);
            fma4(b2f((unsigned short)s[4]), wp[(c8 * 8 + 4) * TPV], acc0);
            fma4(b2f((unsigned short)s[5]), wp[(c8 * 8 + 5) * TPV], acc1);
            fma4(b2f((unsigned short)s[6]), wp[(c8 * 8 + 6) * TPV], acc0);
            fma4(b2f((unsigned short)s[7]), wp[(c8 * 8 + 7) * TPV], acc1);
          }
        }
    float4 acc;
    acc.x = acc0.x + acc1.x; acc.y = acc0.y + acc1.y;
    acc.z = acc0.z + acc1.z; acc.w = acc0.w + acc1.w;
    const float4 r = bn_relu4<Co>(acc, bn, cg);
    short4v o; o[0] = (short)f2b(r.x); o[1] = (short)f2b(r.y);
    o[2] = (short)f2b(r.z); o[3] = (short)f2b(r.w);
    *(short4v*)(out + (size_t)v * Co + cg * 4) = o;
  }
}

// ---------------------------------------------------------------------------
// up: 1-tap conv_transpose; bf16 acts, fp32 weights/math
// ---------------------------------------------------------------------------
template<int Ci, int Co, int LW, int LH>
__global__ void __launch_bounds__(TPB) k_up_b(
    const unsigned short* __restrict__ x, const float* __restrict__ wgt,
    const int* __restrict__ list, const int* __restrict__ cnt,
    unsigned short* __restrict__ out)
{
  constexpr int TPV = Co / 4;
  constexpr int H = 1 << LH, W = 1 << LW;
  const int n = *cnt;
  const int total = n * TPV;
  for (int i = blockIdx.x * TPB + threadIdx.x; i < total; i += gridDim.x * TPB) {
    const int a = i / TPV;
    const int cg = i % TPV;
    const int v = list[a];
    const int w = v & (W - 1), h = (v >> LW) & (H - 1), d = v >> (LW + LH);
    const int kd = 1 - (d & 1), kh = 1 - (h & 1), kw = 1 - (w & 1);
    const int nv = ((((d >> 1) << (LH - 1)) + (h >> 1)) << (LW - 1)) + (w >> 1);
    const int tap = (kd * 2 + kh) * 2 + kw;
    const float4* __restrict__ wp = (const float4*)wgt + (size_t)tap * Ci * TPV + cg;
    const unsigned short* row = x + (size_t)nv * Ci;
    float4 acc0 = make_float4(0.f, 0.f, 0.f, 0.f);
    float4 acc1 = make_float4(0.f, 0.f, 0.f, 0.f);
    #pragma unroll
    for (int c8 = 0; c8 < Ci / 8; ++c8) {
      const short8v s = *(const short8v*)(row + c8 * 8);
      fma4(b2f((unsigned short)s[0]), wp[(c8 * 8 + 0) * TPV], acc0);
      fma4(b2f((unsigned short)s[1]), wp[(c8 * 8 + 1) * TPV], acc1);
      fma4(b2f((unsigned short)s[2]), wp[(c8 * 8 + 2) * TPV], acc0);
      fma4(b2f((unsigned short)s[3]), wp[(c8 * 8 + 3) * TPV], acc1);
      fma4(b2f((unsigned short)s[4]), wp[(c8 * 8 + 4) * TPV], acc0);
      fma4(b2f((unsigned short)s[5]), wp[(c8 * 8 + 5) * TPV], acc1);
      fma4(b2f((unsigned short)s[6]), wp[(c8 * 8 + 6) * TPV], acc0);
      fma4(b2f((unsigned short)s[7]), wp[(c8 * 8 + 7) * TPV], acc1);
    }
    short4v o;
    o[0] = (short)f2b(acc0.x + acc1.x); o[1] = (short)f2b(acc0.y + acc1.y);
    o[2] = (short)f2b(acc0.z + acc1.z); o[3] = (short)f2b(acc0.w + acc1.w);
    *(short4v*)(out + (size_t)v * Co + cg * 4) = o;
  }
}

// ---------------------------------------------------------------------------
// head: bf16 c0, fp32 weights; scatter into 5 output regions
// ---------------------------------------------------------------------------
__global__ void __launch_bounds__(TPB) k_head_b(
    const unsigned short* __restrict__ c0, const float* __restrict__ wh,
    const float* __restrict__ bh, const int* __restrict__ list,
    const int* __restrict__ cnt, float* __restrict__ out)
{
  __shared__ float sw[32 * 45];
  __shared__ float sb[45];
  for (int t = threadIdx.x; t < 32 * 45; t += TPB) sw[t] = wh[t];
  if (threadIdx.x < 45) sb[threadIdx.x] = bh[threadIdx.x];
  __syncthreads();
  const int n = *cnt;
  const int total = n * 45;
  const size_t NV = 524288;
  for (int i = blockIdx.x * TPB + threadIdx.x; i < total; i += gridDim.x * TPB) {
    const int a = i / 45;
    const int j = i % 45;
    const int v = list[a];
    const unsigned short* cp = c0 + (size_t)v * 32;
    float a0 = 0.f, a1 = 0.f;
    #pragma unroll
    for (int c8 = 0; c8 < 4; ++c8) {
      const short8v s = *(const short8v*)(cp + c8 * 8);
      a0 = fmaf(b2f((unsigned short)s[0]), sw[(c8 * 8 + 0) * 45 + j], a0);
      a1 = fmaf(b2f((unsigned short)s[1]), sw[(c8 * 8 + 1) * 45 + j], a1);
      a0 = fmaf(b2f((unsigned short)s[2]), sw[(c8 * 8 + 2) * 45 + j], a0);
      a1 = fmaf(b2f((unsigned short)s[3]), sw[(c8 * 8 + 3) * 45 + j], a1);
      a0 = fmaf(b2f((unsigned short)s[4]), sw[(c8 * 8 + 4) * 45 + j], a0);
      a1 = fmaf(b2f((unsigned short)s[5]), sw[(c8 * 8 + 5) * 45 + j], a1);
      a0 = fmaf(b2f((unsigned short)s[6]), sw[(c8 * 8 + 6) * 45 + j], a0);
      a1 = fmaf(b2f((unsigned short)s[7]), sw[(c8 * 8 + 7) * 45 + j], a1);
    }
    const float val = a0 + a1 + sb[j];
    const int k = j / 9, r = j % 9;
    if (r < 3)
      out[(size_t)v * 15 + k * 3 + r] = val;
    else if (r < 6)
      out[NV * 15 + (size_t)v * 15 + k * 3 + (r - 3)] = fminf(fmaxf(val, -5.f), 3.f);
    else if (r == 6)
      out[NV * 30 + (size_t)v * 5 + k] = val;
    else if (r == 7)
      out[NV * 35 + (size_t)v * 5 + k] = val;
    else
      out[NV * 40 + (size_t)v * 5 + k] = val;
  }
}

// ---------------------------------------------------------------------------
extern "C" void kernel_launch(void* const* d_in, const int* in_sizes, int n_in,
                              void* d_out, int out_size, void* d_ws, size_t ws_size,
                              hipStream_t stream)
{
  (void)in_sizes; (void)n_in;

  const float* x        = (const float*)d_in[0];
  const float* mask0    = (const float*)d_in[1];
  const float* w_enc0   = (const float*)d_in[2];
  const float* bn_enc0  = (const float*)d_in[3];
  const float* w_down0  = (const float*)d_in[4];
  const float* bn_down0 = (const float*)d_in[5];
  const float* w_enc1   = (const float*)d_in[6];
  const float* bn_enc1  = (const float*)d_in[7];
  const float* w_down1  = (const float*)d_in[8];
  const float* bn_down1 = (const float*)d_in[9];
  const float* w_enc2   = (const float*)d_in[10];
  const float* bn_enc2  = (const float*)d_in[11];
  const float* w_down2  = (const float*)d_in[12];
  const float* bn_down2 = (const float*)d_in[13];
  const float* w_bott   = (const float*)d_in[14];
  const float* bn_bott  = (const float*)d_in[15];
  const float* w_up2    = (const float*)d_in[16];
  const float* w_dec2   = (const float*)d_in[17];
  const float* bn_dec2  = (const float*)d_in[18];
  const float* w_up1    = (const float*)d_in[19];
  const float* w_dec1   = (const float*)d_in[20];
  const float* bn_dec1  = (const float*)d_in[21];
  const float* w_up0    = (const float*)d_in[22];
  const float* w_dec0   = (const float*)d_in[23];
  const float* bn_dec0  = (const float*)d_in[24];
  const float* w_head   = (const float*)d_in[25];
  const float* b_head   = (const float*)d_in[26];

  char* ws = (char*)d_ws;
  size_t o = 0;
  auto takeB = [&](size_t bytes) { char* p = ws + o; o += (bytes + 255) & ~(size_t)255; return p; };
  auto takeU = [&](size_t elems) { return (unsigned short*)takeB(elems * 2); };
  auto takeF = [&](size_t elems) { return (float*)takeB(elems * 4); };
  auto takeI = [&](size_t elems) { return (int*)takeB(elems * 4); };

  int*   cnt   = takeI(16);
  int*   bcnt  = takeI(2048);
  int*   boff  = takeI(2048);
  int*   list0 = takeI(524288);
  int*   list1 = takeI(65536);
  int*   list2 = takeI(8192);
  int*   list3 = takeI(1024);
  float* m1    = takeF(65536);
  float* m2    = takeF(8192);
  float* m3    = takeF(1024);
  unsigned short* zb = takeU(256);
  // packed weights (bf16)
  unsigned short* pw_enc0 = takeU(27648);
  unsigned short* pw_enc1 = takeU(110592);
  unsigned short* pw_enc2 = takeU(442368);
  unsigned short* pw_bott = takeU(1769472);
  unsigned short* pw_dec2 = takeU(884736);
  unsigned short* pw_dec1 = takeU(221184);
  unsigned short* pw_dec0 = takeU(55296);
  // bf16 activations
  unsigned short* xb  = takeU(16777216);   // [524288][32] padded x
  unsigned short* e0b = takeU(16777216);
  unsigned short* d0b = takeU(4194304);    // reused as u1b
  unsigned short* e1b = takeU(4194304);
  unsigned short* d1b = takeU(1048576);    // reused as u2b
  unsigned short* e2b = takeU(1048576);
  unsigned short* d2b = takeU(262144);
  unsigned short* bbb = takeU(262144);
  unsigned short* c2b = takeU(1048576);
  unsigned short* c1b = takeU(4194304);
  unsigned short* u0b = takeU(16777216);
  unsigned short* c0b = takeU(16777216);
  if (o > ws_size) return;
  unsigned short* u1b = d0b;
  unsigned short* u2b = d1b;
  int* cnt0 = cnt, *cnt1 = cnt + 1, *cnt2 = cnt + 2, *cnt3 = cnt + 3;

  // zero output + gather-read buffers (inactive rows must read as bf16 zero)
  hipMemsetAsync(d_out, 0, (size_t)out_size * sizeof(float), stream);
  hipMemsetAsync(zb, 0, 256 * 2, stream);
  hipMemsetAsync(e0b, 0, 16777216ull * 2, stream);
  hipMemsetAsync(d0b, 0, 4194304ull * 2, stream);
  hipMemsetAsync(e1b, 0, 4194304ull * 2, stream);
  hipMemsetAsync(d1b, 0, 1048576ull * 2, stream);
  hipMemsetAsync(e2b, 0, 1048576ull * 2, stream);
  hipMemsetAsync(d2b, 0, 262144ull * 2, stream);
  hipMemsetAsync(u0b, 0, 16777216ull * 2, stream);

  auto g = [](long long upper) {
    unsigned b = (unsigned)((upper + TPB - 1) / TPB);
    return dim3(b > 4096u ? 4096u : (b ? b : 1u));
  };

  // weight packs + x convert
  k_packw<20, 32, 0, 32><<<g(27648), TPB, 0, stream>>>(w_enc0, pw_enc0);
  k_packw<64, 64, 0, 64><<<g(110592), TPB, 0, stream>>>(w_enc1, pw_enc1);
  k_packw<128, 128, 0, 128><<<g(442368), TPB, 0, stream>>>(w_enc2, pw_enc2);
  k_packw<256, 256, 0, 256><<<g(1769472), TPB, 0, stream>>>(w_bott, pw_bott);
  k_packw<128, 128, 128, 128><<<g(884736), TPB, 0, stream>>>(w_dec2, pw_dec2);
  k_packw<64, 64, 64, 64><<<g(221184), TPB, 0, stream>>>(w_dec1, pw_dec1);
  k_packw<32, 32, 32, 32><<<g(55296), TPB, 0, stream>>>(w_dec0, pw_dec0);
  k_cvtx<<<dim3(524288 / TPB), TPB, 0, stream>>>(x, xb, 524288);

  // mask pyramid + ordered compaction
  k_maskpool<6, 6, 16><<<g(65536), TPB, 0, stream>>>(mask0, m1);
  k_maskpool<5, 5, 8><<<g(8192), TPB, 0, stream>>>(m1, m2);
  k_maskpool<4, 4, 4><<<g(1024), TPB, 0, stream>>>(m2, m3);
  auto compact = [&](const float* m, int total, int* list, int* cptr) {
    const int nb = total / TPB;
    k_count<<<dim3((unsigned)nb), TPB, 0, stream>>>(m, total, bcnt);
    k_scan<<<dim3(1), 1024, 0, stream>>>(bcnt, nb, boff, cptr);
    k_fill<<<dim3((unsigned)nb), TPB, 0, stream>>>(m, total, boff, list);
  };
  compact(mask0, 524288, list0, cnt0);
  compact(m1,     65536, list1, cnt1);
  compact(m2,      8192, list2, cnt2);
  compact(m3,      1024, list3, cnt3);

  // encoder
  k_subm_m<32, 0, 32, 7, 7, 32><<<dim3(2048), TPB, 0, stream>>>(xb, nullptr, pw_enc0, bn_enc0, list0, cnt0, zb, e0b);
  k_down_b<32, 64, 6, 6, 16><<<g(65536LL * 16), TPB, 0, stream>>>(e0b, w_down0, bn_down0, mask0, list1, cnt1, d0b);
  k_subm_m<64, 0, 64, 6, 6, 16><<<dim3(2048), TPB, 0, stream>>>(d0b, nullptr, pw_enc1, bn_enc1, list1, cnt1, zb, e1b);
  k_down_b<64, 128, 5, 5, 8><<<g(8192LL * 32), TPB, 0, stream>>>(e1b, w_down1, bn_down1, m1, list2, cnt2, d1b);
  k_subm_m<128, 0, 128, 5, 5, 8><<<dim3(256), TPB, 0, stream>>>(d1b, nullptr, pw_enc2, bn_enc2, list2, cnt2, zb, e2b);
  k_down_b<128, 256, 4, 4, 4><<<g(1024LL * 64), TPB, 0, stream>>>(e2b, w_down2, bn_down2, m2, list3, cnt3, d2b);
  // bottleneck
  k_subm_m<256, 0, 256, 4, 4, 4><<<dim3(32), TPB, 0, stream>>>(d2b, nullptr, pw_bott, bn_bott, list3, cnt3, zb, bbb);
  // decoder
  k_up_b<256, 128, 5, 5><<<g(8192LL * 32), TPB, 0, stream>>>(bbb, w_up2, list2, cnt2, u2b);
  k_subm_m<128, 128, 128, 5, 5, 8><<<dim3(256), TPB, 0, stream>>>(u2b, e2b, pw_dec2, bn_dec2, list2, cnt2, zb, c2b);
  k_up_b<128, 64, 6, 6><<<g(65536LL * 16), TPB, 0, stream>>>(c2b, w_up1, list1, cnt1, u1b);
  k_subm_m<64, 64, 64, 6, 6, 16><<<dim3(2048), TPB, 0, stream>>>(u1b, e1b, pw_dec1, bn_dec1, list1, cnt1, zb, c1b);
  k_up_b<64, 32, 7, 7><<<g(524288LL * 8), TPB, 0, stream>>>(c1b, w_up0, list0, cnt0, u0b);
  k_subm_m<32, 32, 32, 7, 7, 32><<<dim3(2048), TPB, 0, stream>>>(u0b, e0b, pw_dec0, bn_dec0, list0, cnt0, zb, c0b);
  // head
  k_head_b<<<g(524288LL * 45), TPB, 0, stream>>>(c0b, w_head, b_head, list0, cnt0, (float*)d_out);
}

// Round 8
// 1078.189 us; speedup vs baseline: 6.1665x; 1.1957x over previous
//
#include <hip/hip_runtime.h>
#include <math.h>

#define TPB 256

typedef __attribute__((ext_vector_type(8))) short short8v;
typedef __attribute__((ext_vector_type(4))) short short4v;
typedef __attribute__((ext_vector_type(4))) float f32x4;

// ---------------------------------------------------------------------------
// bf16 helpers
// ---------------------------------------------------------------------------
__device__ __forceinline__ float b2f(unsigned short u) {
  union { unsigned i; float f; } x; x.i = ((unsigned)u) << 16; return x.f;
}
__device__ __forceinline__ unsigned short f2b(float f) {
  union { float f; unsigned i; } x; x.f = f;
  unsigned r = (x.i + 0x7fffu + ((x.i >> 16) & 1u)) >> 16;
  return (unsigned short)r;
}

__device__ __forceinline__ float4 ld4(const float* p) { return *(const float4*)p; }

__device__ __forceinline__ void fma4(float s, const float4 w, float4& a) {
  a.x = fmaf(s, w.x, a.x); a.y = fmaf(s, w.y, a.y);
  a.z = fmaf(s, w.z, a.z); a.w = fmaf(s, w.w, a.w);
}

template<int Co>
__device__ __forceinline__ float4 bn_relu4(float4 a, const float* __restrict__ bn, int cg) {
  const float4 g = ld4(bn + cg * 4);
  const float4 b = ld4(bn + Co + cg * 4);
  const float4 m = ld4(bn + 2 * Co + cg * 4);
  const float4 v = ld4(bn + 3 * Co + cg * 4);
  float4 r;
  r.x = fmaxf((a.x - m.x) * (g.x * rsqrtf(v.x + 1e-5f)) + b.x, 0.f);
  r.y = fmaxf((a.y - m.y) * (g.y * rsqrtf(v.y + 1e-5f)) + b.y, 0.f);
  r.z = fmaxf((a.z - m.z) * (g.z * rsqrtf(v.z + 1e-5f)) + b.z, 0.f);
  r.w = fmaxf((a.w - m.w) * (g.w * rsqrtf(v.w + 1e-5f)) + b.w, 0.f);
  return r;
}

// ---------------------------------------------------------------------------
// mask pyramid
// ---------------------------------------------------------------------------
template<int LW, int LH, int D>
__global__ void __launch_bounds__(TPB) k_maskpool(const float* __restrict__ mf,
                                                  float* __restrict__ mc) {
  constexpr int W = 1 << LW, H = 1 << LH;
  constexpr int total = D * H * W;
  const int v = blockIdx.x * TPB + threadIdx.x;
  if (v >= total) return;
  const int w = v & (W - 1), h = (v >> LW) & (H - 1), d = v >> (LW + LH);
  float mp = 0.f;
  #pragma unroll
  for (int dz = 0; dz < 2; ++dz)
    #pragma unroll
    for (int hz = 0; hz < 2; ++hz)
      #pragma unroll
      for (int wz = 0; wz < 2; ++wz)
        mp = fmaxf(mp, mf[((((2*d+dz) << (LH+1)) + (2*h+hz)) << (LW+1)) + (2*w+wz)]);
  mc[v] = mp;
}

// ---------------------------------------------------------------------------
// deterministic ordered compaction: count -> scan -> fill
// ---------------------------------------------------------------------------
__global__ void __launch_bounds__(TPB) k_count(const float* __restrict__ m, int total,
                                               int* __restrict__ bcount) {
  const int v = blockIdx.x * TPB + threadIdx.x;
  const bool act = (v < total) && (m[v] != 0.f);
  const unsigned long long b = __ballot(act);
  __shared__ int wc[TPB / 64];
  const int wid = threadIdx.x >> 6;
  if ((threadIdx.x & 63) == 0) wc[wid] = __popcll(b);
  __syncthreads();
  if (threadIdx.x == 0) bcount[blockIdx.x] = wc[0] + wc[1] + wc[2] + wc[3];
}

__global__ void __launch_bounds__(1024) k_scan(const int* __restrict__ bc, int nb,
                                               int* __restrict__ boff, int* __restrict__ total) {
  __shared__ int part[1024];
  const int t = threadIdx.x;
  const int a0 = (2 * t     < nb) ? bc[2 * t]     : 0;
  const int a1 = (2 * t + 1 < nb) ? bc[2 * t + 1] : 0;
  part[t] = a0 + a1;
  __syncthreads();
  for (int off = 1; off < 1024; off <<= 1) {
    const int tmp = (t >= off) ? part[t - off] : 0;
    __syncthreads();
    part[t] += tmp;
    __syncthreads();
  }
  const int excl = (t == 0) ? 0 : part[t - 1];
  if (2 * t     < nb) boff[2 * t]     = excl;
  if (2 * t + 1 < nb) boff[2 * t + 1] = excl + a0;
  if (t == 1023) *total = part[1023];
}

__global__ void __launch_bounds__(TPB) k_fill(const float* __restrict__ m, int total,
                                              const int* __restrict__ boff,
                                              int* __restrict__ list) {
  const int v = blockIdx.x * TPB + threadIdx.x;
  const bool act = (v < total) && (m[v] != 0.f);
  const unsigned long long b = __ballot(act);
  const int wid = threadIdx.x >> 6, lane = threadIdx.x & 63;
  __shared__ int wc[TPB / 64];
  __shared__ int wbase[TPB / 64];
  if (lane == 0) wc[wid] = __popcll(b);
  __syncthreads();
  if (threadIdx.x == 0) {
    int s = boff[blockIdx.x];
    #pragma unroll
    for (int i = 0; i < TPB / 64; ++i) { wbase[i] = s; s += wc[i]; }
  }
  __syncthreads();
  if (act) {
    const int rank = __popcll(b & ((1ull << lane) - 1ull));
    list[wbase[wid] + rank] = v;
  }
}

// ---------------------------------------------------------------------------
// x: fp32 [NV][20] -> bf16 [NV][32] (zero-padded channels)
// ---------------------------------------------------------------------------
__global__ void __launch_bounds__(TPB) k_cvtx(const float* __restrict__ x,
                                              unsigned short* __restrict__ xb, int NV) {
  const int v = blockIdx.x * TPB + threadIdx.x;
  if (v >= NV) return;
  const float* r = x + (size_t)v * 20;
  unsigned short* o = xb + (size_t)v * 32;
  #pragma unroll
  for (int c4 = 0; c4 < 5; ++c4) {
    const float4 f = ld4(r + c4 * 4);
    short4v s; s[0] = (short)f2b(f.x); s[1] = (short)f2b(f.y);
    s[2] = (short)f2b(f.z); s[3] = (short)f2b(f.w);
    *(short4v*)(o + c4 * 4) = s;
  }
  const short4v z = {0, 0, 0, 0};
  *(short4v*)(o + 20) = z; *(short4v*)(o + 24) = z; *(short4v*)(o + 28) = z;
}

// ---------------------------------------------------------------------------
// weight pack: fp32 [27][C1r+C2][Co] -> bf16 MFMA-B fragments.
// ---------------------------------------------------------------------------
template<int C1r, int C1p, int C2, int Co>
__global__ void __launch_bounds__(TPB) k_packw(const float* __restrict__ w,
                                               unsigned short* __restrict__ pw) {
  constexpr int NT = Co / 16;
  constexpr int NKC = (C1p + C2) / 32;
  constexpr int total = 27 * NT * NKC * 512;
  const int idx = blockIdx.x * TPB + threadIdx.x;
  if (idx >= total) return;
  const int j = idx & 7;
  const int l = (idx >> 3) & 63;
  int rest = idx >> 9;
  const int kc = rest % NKC; rest /= NKC;
  const int nt = rest % NT;
  const int t = rest / NT;
  const int k = kc * 32 + ((l >> 4) << 3) + j;
  const int n = nt * 16 + (l & 15);
  int ksrc;
  if (k < C1p) ksrc = (k < C1r) ? k : -1;
  else         ksrc = C1r + (k - C1p);
  const float val = (ksrc < 0) ? 0.f : w[((size_t)t * (C1r + C2) + ksrc) * Co + n];
  pw[idx] = f2b(val);
}

// ---------------------------------------------------------------------------
// subm via MFMA (full 27 taps): conv + BN + ReLU, bf16 in/out, fp32 accum.
// ---------------------------------------------------------------------------
template<int C1p, int C2, int Co, int LW, int LH, int D>
__global__ void __launch_bounds__(TPB) k_subm_m(
    const unsigned short* __restrict__ xb1, const unsigned short* __restrict__ xb2,
    const unsigned short* __restrict__ pw, const float* __restrict__ bn,
    const int* __restrict__ list, const int* __restrict__ cnt,
    const unsigned short* __restrict__ zb, unsigned short* __restrict__ out)
{
  constexpr int NT = Co / 16;
  constexpr int NKC1 = C1p / 32;
  constexpr int NKC = (C1p + C2) / 32;
  constexpr int MH = (NT >= 4) ? 1 : 2;
  constexpr int NTPW = (NT >= 4) ? NT / 4 : 1;
  constexpr int MVB = 32 * MH;
  constexpr int H = 1 << LH, W = 1 << LW;

  const int n = *cnt;
  if (n == 0) return;
  const int nmt = (n + MVB - 1) / MVB;
  const int wv = threadIdx.x >> 6, l = threadIdx.x & 63;
  const int mhalf = (MH == 2) ? (wv >> 1) : 0;
  const int nt0   = (MH == 2) ? (wv & 1) : wv * NTPW;
  const int lm = l & 15, lg = l >> 4;

  for (int mt = blockIdx.x; mt < nmt; mt += gridDim.x) {
    const int r0 = mt * MVB + mhalf * 32;
    int wx[2], hy[2], dzz[2];
    #pragma unroll
    for (int h2 = 0; h2 < 2; ++h2) {
      const int g = min(r0 + h2 * 16 + lm, n - 1);
      const int v = list[g];
      wx[h2] = v & (W - 1); hy[h2] = (v >> LW) & (H - 1); dzz[h2] = v >> (LW + LH);
    }
    f32x4 acc[NTPW][2];
    #pragma unroll
    for (int q = 0; q < NTPW; ++q)
      #pragma unroll
      for (int h2 = 0; h2 < 2; ++h2)
        acc[q][h2] = (f32x4){0.f, 0.f, 0.f, 0.f};

    for (int t = 0; t < 27; ++t) {
      const int kd = t / 9, kh = (t / 3) % 3, kw = t % 3;
      const unsigned short* p1[2];
      const unsigned short* p2[2];
      #pragma unroll
      for (int h2 = 0; h2 < 2; ++h2) {
        const int zd0 = dzz[h2] + kd - 1, zh0 = hy[h2] + kh - 1, zw0 = wx[h2] + kw - 1;
        const bool inb = ((unsigned)zd0 < (unsigned)D) &
                         ((unsigned)zh0 < (unsigned)H) &
                         ((unsigned)zw0 < (unsigned)W);
        const int zd = min(max(zd0, 0), D - 1);
        const int zh = min(max(zh0, 0), H - 1);
        const int zw = min(max(zw0, 0), W - 1);
        const int nv = (((zd << LH) + zh) << LW) + zw;
        p1[h2] = (inb ? xb1 + (size_t)nv * C1p : zb) + lg * 8;
        if constexpr (C2 > 0) p2[h2] = (inb ? xb2 + (size_t)nv * C2 : zb) + lg * 8;
      }
      #pragma unroll
      for (int kc = 0; kc < NKC; ++kc) {
        short8v a0, a1;
        if (C2 == 0 || kc < NKC1) {
          const int coff = kc * 32;
          a0 = *(const short8v*)(p1[0] + coff);
          a1 = *(const short8v*)(p1[1] + coff);
        } else {
          const int coff = (kc - NKC1) * 32;
          a0 = *(const short8v*)(p2[0] + coff);
          a1 = *(const short8v*)(p2[1] + coff);
        }
        #pragma unroll
        for (int q = 0; q < NTPW; ++q) {
          const int nt = nt0 + q;
          const short8v b = *(const short8v*)(pw + ((((size_t)t * NT + nt) * NKC + kc) << 9) + l * 8);
          acc[q][0] = __builtin_amdgcn_mfma_f32_16x16x32_bf16(a0, b, acc[q][0], 0, 0, 0);
          acc[q][1] = __builtin_amdgcn_mfma_f32_16x16x32_bf16(a1, b, acc[q][1], 0, 0, 0);
        }
      }
    }
    #pragma unroll
    for (int q = 0; q < NTPW; ++q) {
      const int nt = nt0 + q;
      const int co = nt * 16 + lm;
      const float sc = bn[co] * rsqrtf(bn[3 * Co + co] + 1e-5f);
      const float sh = bn[Co + co] - bn[2 * Co + co] * sc;
      #pragma unroll
      for (int h2 = 0; h2 < 2; ++h2)
        #pragma unroll
        for (int i = 0; i < 4; ++i) {
          const int g = r0 + h2 * 16 + lg * 4 + i;
          if (g < n) {
            const int v = list[g];
            const float y = fmaxf(acc[q][h2][i] * sc + sh, 0.f);
            out[(size_t)v * Co + co] = f2b(y);
          }
        }
    }
  }
}

// ---------------------------------------------------------------------------
// subm via MFMA, TAP-SPLIT: blockIdx.y = s handles taps [s*TPS,(s+1)*TPS).
// Writes RAW fp32 partials to pbuf[s][listpos][Co]; reduce applies BN.
// ---------------------------------------------------------------------------
template<int C1p, int C2, int Co, int LW, int LH, int D, int NSPLIT, int CAP>
__global__ void __launch_bounds__(TPB) k_subm_mp(
    const unsigned short* __restrict__ xb1, const unsigned short* __restrict__ xb2,
    const unsigned short* __restrict__ pw,
    const int* __restrict__ list, const int* __restrict__ cnt,
    const unsigned short* __restrict__ zb, float* __restrict__ pbuf)
{
  constexpr int NT = Co / 16;
  constexpr int NKC1 = C1p / 32;
  constexpr int NKC = (C1p + C2) / 32;
  constexpr int MH = (NT >= 4) ? 1 : 2;
  constexpr int NTPW = (NT >= 4) ? NT / 4 : 1;
  constexpr int MVB = 32 * MH;
  constexpr int TPS = 27 / NSPLIT;
  constexpr int H = 1 << LH, W = 1 << LW;

  const int n = *cnt;
  if (n == 0) return;
  const int nmt = (n + MVB - 1) / MVB;
  const int s = blockIdx.y;
  const int wv = threadIdx.x >> 6, l = threadIdx.x & 63;
  const int mhalf = (MH == 2) ? (wv >> 1) : 0;
  const int nt0   = (MH == 2) ? (wv & 1) : wv * NTPW;
  const int lm = l & 15, lg = l >> 4;

  for (int mt = blockIdx.x; mt < nmt; mt += gridDim.x) {
    const int r0 = mt * MVB + mhalf * 32;
    int wx[2], hy[2], dzz[2];
    #pragma unroll
    for (int h2 = 0; h2 < 2; ++h2) {
      const int g = min(r0 + h2 * 16 + lm, n - 1);
      const int v = list[g];
      wx[h2] = v & (W - 1); hy[h2] = (v >> LW) & (H - 1); dzz[h2] = v >> (LW + LH);
    }
    f32x4 acc[NTPW][2];
    #pragma unroll
    for (int q = 0; q < NTPW; ++q)
      #pragma unroll
      for (int h2 = 0; h2 < 2; ++h2)
        acc[q][h2] = (f32x4){0.f, 0.f, 0.f, 0.f};

    for (int t = s * TPS; t < (s + 1) * TPS; ++t) {
      const int kd = t / 9, kh = (t / 3) % 3, kw = t % 3;
      const unsigned short* p1[2];
      const unsigned short* p2[2];
      #pragma unroll
      for (int h2 = 0; h2 < 2; ++h2) {
        const int zd0 = dzz[h2] + kd - 1, zh0 = hy[h2] + kh - 1, zw0 = wx[h2] + kw - 1;
        const bool inb = ((unsigned)zd0 < (unsigned)D) &
                         ((unsigned)zh0 < (unsigned)H) &
                         ((unsigned)zw0 < (unsigned)W);
        const int zd = min(max(zd0, 0), D - 1);
        const int zh = min(max(zh0, 0), H - 1);
        const int zw = min(max(zw0, 0), W - 1);
        const int nv = (((zd << LH) + zh) << LW) + zw;
        p1[h2] = (inb ? xb1 + (size_t)nv * C1p : zb) + lg * 8;
        if constexpr (C2 > 0) p2[h2] = (inb ? xb2 + (size_t)nv * C2 : zb) + lg * 8;
      }
      #pragma unroll
      for (int kc = 0; kc < NKC; ++kc) {
        short8v a0, a1;
        if (C2 == 0 || kc < NKC1) {
          const int coff = kc * 32;
          a0 = *(const short8v*)(p1[0] + coff);
          a1 = *(const short8v*)(p1[1] + coff);
        } else {
          const int coff = (kc - NKC1) * 32;
          a0 = *(const short8v*)(p2[0] + coff);
          a1 = *(const short8v*)(p2[1] + coff);
        }
        #pragma unroll
        for (int q = 0; q < NTPW; ++q) {
          const int nt = nt0 + q;
          const short8v b = *(const short8v*)(pw + ((((size_t)t * NT + nt) * NKC + kc) << 9) + l * 8);
          acc[q][0] = __builtin_amdgcn_mfma_f32_16x16x32_bf16(a0, b, acc[q][0], 0, 0, 0);
          acc[q][1] = __builtin_amdgcn_mfma_f32_16x16x32_bf16(a1, b, acc[q][1], 0, 0, 0);
        }
      }
    }
    #pragma unroll
    for (int q = 0; q < NTPW; ++q) {
      const int co = (nt0 + q) * 16 + lm;
      #pragma unroll
      for (int h2 = 0; h2 < 2; ++h2)
        #pragma unroll
        for (int i = 0; i < 4; ++i) {
          const int g = r0 + h2 * 16 + lg * 4 + i;
          if (g < n)
            pbuf[((size_t)s * CAP + g) * Co + co] = acc[q][h2][i];
        }
    }
  }
}

// sum NSPLIT fp32 partials in fixed order + BN + ReLU -> bf16 out
template<int Co, int NSPLIT, int CAP>
__global__ void __launch_bounds__(TPB) k_reduce_bnb(
    const float* __restrict__ pbuf, const float* __restrict__ bn,
    const int* __restrict__ list, const int* __restrict__ cnt,
    unsigned short* __restrict__ out)
{
  constexpr int TPV = Co / 4;
  const int n = *cnt;
  const int total = n * TPV;
  for (int i = blockIdx.x * TPB + threadIdx.x; i < total; i += gridDim.x * TPB) {
    const int a = i / TPV;
    const int cg = i % TPV;
    float4 acc = make_float4(0.f, 0.f, 0.f, 0.f);
    #pragma unroll
    for (int s = 0; s < NSPLIT; ++s) {
      const float4 p = ld4(pbuf + ((size_t)s * CAP + a) * Co + cg * 4);
      acc.x += p.x; acc.y += p.y; acc.z += p.z; acc.w += p.w;
    }
    const int v = list[a];
    const float4 r = bn_relu4<Co>(acc, bn, cg);
    short4v o; o[0] = (short)f2b(r.x); o[1] = (short)f2b(r.y);
    o[2] = (short)f2b(r.z); o[3] = (short)f2b(r.w);
    *(short4v*)(out + (size_t)v * Co + cg * 4) = o;
  }
}

// ---------------------------------------------------------------------------
// down: 2x2x2 stride-2 conv + BN + ReLU; bf16 acts, fp32 weights/math
// ---------------------------------------------------------------------------
template<int Ci, int Co, int LW, int LH, int D>
__global__ void __launch_bounds__(TPB) k_down_b(
    const unsigned short* __restrict__ x, const float* __restrict__ wgt,
    const float* __restrict__ bn, const float* __restrict__ mfine,
    const int* __restrict__ list, const int* __restrict__ cnt,
    unsigned short* __restrict__ out)
{
  constexpr int TPV = Co / 4;
  constexpr int H = 1 << LH, W = 1 << LW;
  const int n = *cnt;
  const int total = n * TPV;
  for (int i = blockIdx.x * TPB + threadIdx.x; i < total; i += gridDim.x * TPB) {
    const int a = i / TPV;
    const int cg = i % TPV;
    const int v = list[a];
    const int w = v & (W - 1), h = (v >> LW) & (H - 1), d = v >> (LW + LH);
    float4 acc0 = make_float4(0.f, 0.f, 0.f, 0.f);
    float4 acc1 = make_float4(0.f, 0.f, 0.f, 0.f);
    #pragma unroll
    for (int kd = 0; kd < 2; ++kd)
      #pragma unroll
      for (int kh = 0; kh < 2; ++kh)
        #pragma unroll
        for (int kw = 0; kw < 2; ++kw) {
          const int nv = ((((2*d+kd) << (LH+1)) + (2*h+kh)) << (LW+1)) + (2*w+kw);
          if (mfine[nv] == 0.f) continue;
          const int tap = (kd * 2 + kh) * 2 + kw;
          const float4* __restrict__ wp = (const float4*)wgt + (size_t)tap * Ci * TPV + cg;
          const unsigned short* row = x + (size_t)nv * Ci;
          #pragma unroll
          for (int c8 = 0; c8 < Ci / 8; ++c8) {
            const short8v s = *(const short8v*)(row + c8 * 8);
            fma4(b2f((unsigned short)s[0]), wp[(c8 * 8 + 0) * TPV], acc0);
            fma4(b2f((unsigned short)s[1]), wp[(c8 * 8 + 1) * TPV], acc1);
            fma4(b2f((unsigned short)s[2]), wp[(c8 * 8 + 2) * TPV], acc0);
            fma4(b2f((unsigned short)s[3]), wp[(c8 * 8 + 3) * TPV], acc1);
            fma4(b2f((unsigned short)s[4]), wp[(c8 * 8 + 4) * TPV], acc0);
            fma4(b2f((unsigned short)s[5]), wp[(c8 * 8 + 5) * TPV], acc1);
            fma4(b2f((unsigned short)s[6]), wp[(c8 * 8 + 6) * TPV], acc0);
            fma4(b2f((unsigned short)s[7]), wp[(c8 * 8 + 7) * TPV], acc1);
          }
        }
    float4 acc;
    acc.x = acc0.x + acc1.x; acc.y = acc0.y + acc1.y;
    acc.z = acc0.z + acc1.z; acc.w = acc0.w + acc1.w;
    const float4 r = bn_relu4<Co>(acc, bn, cg);
    short4v o; o[0] = (short)f2b(r.x); o[1] = (short)f2b(r.y);
    o[2] = (short)f2b(r.z); o[3] = (short)f2b(r.w);
    *(short4v*)(out + (size_t)v * Co + cg * 4) = o;
  }
}

// ---------------------------------------------------------------------------
// up: 1-tap conv_transpose; bf16 acts, fp32 weights/math
// ---------------------------------------------------------------------------
template<int Ci, int Co, int LW, int LH>
__global__ void __launch_bounds__(TPB) k_up_b(
    const unsigned short* __restrict__ x, const float* __restrict__ wgt,
    const int* __restrict__ list, const int* __restrict__ cnt,
    unsigned short* __restrict__ out)
{
  constexpr int TPV = Co / 4;
  constexpr int H = 1 << LH, W = 1 << LW;
  const int n = *cnt;
  const int total = n * TPV;
  for (int i = blockIdx.x * TPB + threadIdx.x; i < total; i += gridDim.x * TPB) {
    const int a = i / TPV;
    const int cg = i % TPV;
    const int v = list[a];
    const int w = v & (W - 1), h = (v >> LW) & (H - 1), d = v >> (LW + LH);
    const int kd = 1 - (d & 1), kh = 1 - (h & 1), kw = 1 - (w & 1);
    const int nv = ((((d >> 1) << (LH - 1)) + (h >> 1)) << (LW - 1)) + (w >> 1);
    const int tap = (kd * 2 + kh) * 2 + kw;
    const float4* __restrict__ wp = (const float4*)wgt + (size_t)tap * Ci * TPV + cg;
    const unsigned short* row = x + (size_t)nv * Ci;
    float4 acc0 = make_float4(0.f, 0.f, 0.f, 0.f);
    float4 acc1 = make_float4(0.f, 0.f, 0.f, 0.f);
    #pragma unroll
    for (int c8 = 0; c8 < Ci / 8; ++c8) {
      const short8v s = *(const short8v*)(row + c8 * 8);
      fma4(b2f((unsigned short)s[0]), wp[(c8 * 8 + 0) * TPV], acc0);
      fma4(b2f((unsigned short)s[1]), wp[(c8 * 8 + 1) * TPV], acc1);
      fma4(b2f((unsigned short)s[2]), wp[(c8 * 8 + 2) * TPV], acc0);
      fma4(b2f((unsigned short)s[3]), wp[(c8 * 8 + 3) * TPV], acc1);
      fma4(b2f((unsigned short)s[4]), wp[(c8 * 8 + 4) * TPV], acc0);
      fma4(b2f((unsigned short)s[5]), wp[(c8 * 8 + 5) * TPV], acc1);
      fma4(b2f((unsigned short)s[6]), wp[(c8 * 8 + 6) * TPV], acc0);
      fma4(b2f((unsigned short)s[7]), wp[(c8 * 8 + 7) * TPV], acc1);
    }
    short4v o;
    o[0] = (short)f2b(acc0.x + acc1.x); o[1] = (short)f2b(acc0.y + acc1.y);
    o[2] = (short)f2b(acc0.z + acc1.z); o[3] = (short)f2b(acc0.w + acc1.w);
    *(short4v*)(out + (size_t)v * Co + cg * 4) = o;
  }
}

// ---------------------------------------------------------------------------
// head: bf16 c0, fp32 weights; scatter into 5 output regions
// ---------------------------------------------------------------------------
__global__ void __launch_bounds__(TPB) k_head_b(
    const unsigned short* __restrict__ c0, const float* __restrict__ wh,
    const float* __restrict__ bh, const int* __restrict__ list,
    const int* __restrict__ cnt, float* __restrict__ out)
{
  __shared__ float sw[32 * 45];
  __shared__ float sb[45];
  for (int t = threadIdx.x; t < 32 * 45; t += TPB) sw[t] = wh[t];
  if (threadIdx.x < 45) sb[threadIdx.x] = bh[threadIdx.x];
  __syncthreads();
  const int n = *cnt;
  const int total = n * 45;
  const size_t NV = 524288;
  for (int i = blockIdx.x * TPB + threadIdx.x; i < total; i += gridDim.x * TPB) {
    const int a = i / 45;
    const int j = i % 45;
    const int v = list[a];
    const unsigned short* cp = c0 + (size_t)v * 32;
    float a0 = 0.f, a1 = 0.f;
    #pragma unroll
    for (int c8 = 0; c8 < 4; ++c8) {
      const short8v s = *(const short8v*)(cp + c8 * 8);
      a0 = fmaf(b2f((unsigned short)s[0]), sw[(c8 * 8 + 0) * 45 + j], a0);
      a1 = fmaf(b2f((unsigned short)s[1]), sw[(c8 * 8 + 1) * 45 + j], a1);
      a0 = fmaf(b2f((unsigned short)s[2]), sw[(c8 * 8 + 2) * 45 + j], a0);
      a1 = fmaf(b2f((unsigned short)s[3]), sw[(c8 * 8 + 3) * 45 + j], a1);
      a0 = fmaf(b2f((unsigned short)s[4]), sw[(c8 * 8 + 4) * 45 + j], a0);
      a1 = fmaf(b2f((unsigned short)s[5]), sw[(c8 * 8 + 5) * 45 + j], a1);
      a0 = fmaf(b2f((unsigned short)s[6]), sw[(c8 * 8 + 6) * 45 + j], a0);
      a1 = fmaf(b2f((unsigned short)s[7]), sw[(c8 * 8 + 7) * 45 + j], a1);
    }
    const float val = a0 + a1 + sb[j];
    const int k = j / 9, r = j % 9;
    if (r < 3)
      out[(size_t)v * 15 + k * 3 + r] = val;
    else if (r < 6)
      out[NV * 15 + (size_t)v * 15 + k * 3 + (r - 3)] = fminf(fmaxf(val, -5.f), 3.f);
    else if (r == 6)
      out[NV * 30 + (size_t)v * 5 + k] = val;
    else if (r == 7)
      out[NV * 35 + (size_t)v * 5 + k] = val;
    else
      out[NV * 40 + (size_t)v * 5 + k] = val;
  }
}

// ---------------------------------------------------------------------------
extern "C" void kernel_launch(void* const* d_in, const int* in_sizes, int n_in,
                              void* d_out, int out_size, void* d_ws, size_t ws_size,
                              hipStream_t stream)
{
  (void)in_sizes; (void)n_in;

  const float* x        = (const float*)d_in[0];
  const float* mask0    = (const float*)d_in[1];
  const float* w_enc0   = (const float*)d_in[2];
  const float* bn_enc0  = (const float*)d_in[3];
  const float* w_down0  = (const float*)d_in[4];
  const float* bn_down0 = (const float*)d_in[5];
  const float* w_enc1   = (const float*)d_in[6];
  const float* bn_enc1  = (const float*)d_in[7];
  const float* w_down1  = (const float*)d_in[8];
  const float* bn_down1 = (const float*)d_in[9];
  const float* w_enc2   = (const float*)d_in[10];
  const float* bn_enc2  = (const float*)d_in[11];
  const float* w_down2  = (const float*)d_in[12];
  const float* bn_down2 = (const float*)d_in[13];
  const float* w_bott   = (const float*)d_in[14];
  const float* bn_bott  = (const float*)d_in[15];
  const float* w_up2    = (const float*)d_in[16];
  const float* w_dec2   = (const float*)d_in[17];
  const float* bn_dec2  = (const float*)d_in[18];
  const float* w_up1    = (const float*)d_in[19];
  const float* w_dec1   = (const float*)d_in[20];
  const float* bn_dec1  = (const float*)d_in[21];
  const float* w_up0    = (const float*)d_in[22];
  const float* w_dec0   = (const float*)d_in[23];
  const float* bn_dec0  = (const float*)d_in[24];
  const float* w_head   = (const float*)d_in[25];
  const float* b_head   = (const float*)d_in[26];

  char* ws = (char*)d_ws;
  size_t o = 0;
  auto takeB = [&](size_t bytes) { char* p = ws + o; o += (bytes + 255) & ~(size_t)255; return p; };
  auto takeU = [&](size_t elems) { return (unsigned short*)takeB(elems * 2); };
  auto takeF = [&](size_t elems) { return (float*)takeB(elems * 4); };
  auto takeI = [&](size_t elems) { return (int*)takeB(elems * 4); };

  int*   cnt   = takeI(16);
  int*   bcnt  = takeI(2048);
  int*   boff  = takeI(2048);
  int*   list0 = takeI(524288);
  int*   list1 = takeI(65536);
  int*   list2 = takeI(8192);
  int*   list3 = takeI(1024);
  float* m1    = takeF(65536);
  float* m2    = takeF(8192);
  float* m3    = takeF(1024);
  unsigned short* zb = takeU(256);
  float* pbuf = takeF(3145728);            // K-split partials (max: 3*8192*128)
  // packed weights (bf16)
  unsigned short* pw_enc0 = takeU(27648);
  unsigned short* pw_enc1 = takeU(110592);
  unsigned short* pw_enc2 = takeU(442368);
  unsigned short* pw_bott = takeU(1769472);
  unsigned short* pw_dec2 = takeU(884736);
  unsigned short* pw_dec1 = takeU(221184);
  unsigned short* pw_dec0 = takeU(55296);
  // bf16 activations
  unsigned short* xb  = takeU(16777216);
  unsigned short* e0b = takeU(16777216);
  unsigned short* d0b = takeU(4194304);    // reused as u1b
  unsigned short* e1b = takeU(4194304);
  unsigned short* d1b = takeU(1048576);    // reused as u2b
  unsigned short* e2b = takeU(1048576);
  unsigned short* d2b = takeU(262144);
  unsigned short* bbb = takeU(262144);
  unsigned short* c2b = takeU(1048576);
  unsigned short* c1b = takeU(4194304);
  unsigned short* u0b = takeU(16777216);
  unsigned short* c0b = takeU(16777216);
  if (o > ws_size) return;
  unsigned short* u1b = d0b;
  unsigned short* u2b = d1b;
  int* cnt0 = cnt, *cnt1 = cnt + 1, *cnt2 = cnt + 2, *cnt3 = cnt + 3;

  hipMemsetAsync(d_out, 0, (size_t)out_size * sizeof(float), stream);
  hipMemsetAsync(zb, 0, 256 * 2, stream);
  hipMemsetAsync(e0b, 0, 16777216ull * 2, stream);
  hipMemsetAsync(d0b, 0, 4194304ull * 2, stream);
  hipMemsetAsync(e1b, 0, 4194304ull * 2, stream);
  hipMemsetAsync(d1b, 0, 1048576ull * 2, stream);
  hipMemsetAsync(e2b, 0, 1048576ull * 2, stream);
  hipMemsetAsync(d2b, 0, 262144ull * 2, stream);
  hipMemsetAsync(u0b, 0, 16777216ull * 2, stream);

  auto g = [](long long upper) {
    unsigned b = (unsigned)((upper + TPB - 1) / TPB);
    return dim3(b > 4096u ? 4096u : (b ? b : 1u));
  };

  // weight packs + x convert
  k_packw<20, 32, 0, 32><<<g(27648), TPB, 0, stream>>>(w_enc0, pw_enc0);
  k_packw<64, 64, 0, 64><<<g(110592), TPB, 0, stream>>>(w_enc1, pw_enc1);
  k_packw<128, 128, 0, 128><<<g(442368), TPB, 0, stream>>>(w_enc2, pw_enc2);
  k_packw<256, 256, 0, 256><<<g(1769472), TPB, 0, stream>>>(w_bott, pw_bott);
  k_packw<128, 128, 128, 128><<<g(884736), TPB, 0, stream>>>(w_dec2, pw_dec2);
  k_packw<64, 64, 64, 64><<<g(221184), TPB, 0, stream>>>(w_dec1, pw_dec1);
  k_packw<32, 32, 32, 32><<<g(55296), TPB, 0, stream>>>(w_dec0, pw_dec0);
  k_cvtx<<<dim3(524288 / TPB), TPB, 0, stream>>>(x, xb, 524288);

  // mask pyramid + ordered compaction
  k_maskpool<6, 6, 16><<<g(65536), TPB, 0, stream>>>(mask0, m1);
  k_maskpool<5, 5, 8><<<g(8192), TPB, 0, stream>>>(m1, m2);
  k_maskpool<4, 4, 4><<<g(1024), TPB, 0, stream>>>(m2, m3);
  auto compact = [&](const float* m, int total, int* list, int* cptr) {
    const int nb = total / TPB;
    k_count<<<dim3((unsigned)nb), TPB, 0, stream>>>(m, total, bcnt);
    k_scan<<<dim3(1), 1024, 0, stream>>>(bcnt, nb, boff, cptr);
    k_fill<<<dim3((unsigned)nb), TPB, 0, stream>>>(m, total, boff, list);
  };
  compact(mask0, 524288, list0, cnt0);
  compact(m1,     65536, list1, cnt1);
  compact(m2,      8192, list2, cnt2);
  compact(m3,      1024, list3, cnt3);

  // encoder
  k_subm_m<32, 0, 32, 7, 7, 32><<<dim3(2048), TPB, 0, stream>>>(xb, nullptr, pw_enc0, bn_enc0, list0, cnt0, zb, e0b);
  k_down_b<32, 64, 6, 6, 16><<<g(65536LL * 16), TPB, 0, stream>>>(e0b, w_down0, bn_down0, mask0, list1, cnt1, d0b);
  k_subm_m<64, 0, 64, 6, 6, 16><<<dim3(2048), TPB, 0, stream>>>(d0b, nullptr, pw_enc1, bn_enc1, list1, cnt1, zb, e1b);
  k_down_b<64, 128, 5, 5, 8><<<g(8192LL * 32), TPB, 0, stream>>>(e1b, w_down1, bn_down1, m1, list2, cnt2, d1b);
  // enc2: tap-split x3
  k_subm_mp<128, 0, 128, 5, 5, 8, 3, 8192><<<dim3(256, 3), TPB, 0, stream>>>(d1b, nullptr, pw_enc2, list2, cnt2, zb, pbuf);
  k_reduce_bnb<128, 3, 8192><<<g(8192LL * 32), TPB, 0, stream>>>(pbuf, bn_enc2, list2, cnt2, e2b);
  k_down_b<128, 256, 4, 4, 4><<<g(1024LL * 64), TPB, 0, stream>>>(e2b, w_down2, bn_down2, m2, list3, cnt3, d2b);
  // bottleneck: tap-split x9
  k_subm_mp<256, 0, 256, 4, 4, 4, 9, 1024><<<dim3(32, 9), TPB, 0, stream>>>(d2b, nullptr, pw_bott, list3, cnt3, zb, pbuf);
  k_reduce_bnb<256, 9, 1024><<<g(1024LL * 64), TPB, 0, stream>>>(pbuf, bn_bott, list3, cnt3, bbb);
  // decoder
  k_up_b<256, 128, 5, 5><<<g(8192LL * 32), TPB, 0, stream>>>(bbb, w_up2, list2, cnt2, u2b);
  // dec2: tap-split x3 (concat u2|e2)
  k_subm_mp<128, 128, 128, 5, 5, 8, 3, 8192><<<dim3(256, 3), TPB, 0, stream>>>(u2b, e2b, pw_dec2, list2, cnt2, zb, pbuf);
  k_reduce_bnb<128, 3, 8192><<<g(8192LL * 32), TPB, 0, stream>>>(pbuf, bn_dec2, list2, cnt2, c2b);
  k_up_b<128, 64, 6, 6><<<g(65536LL * 16), TPB, 0, stream>>>(c2b, w_up1, list1, cnt1, u1b);
  k_subm_m<64, 64, 64, 6, 6, 16><<<dim3(2048), TPB, 0, stream>>>(u1b, e1b, pw_dec1, bn_dec1, list1, cnt1, zb, c1b);
  k_up_b<64, 32, 7, 7><<<g(524288LL * 8), TPB, 0, stream>>>(c1b, w_up0, list0, cnt0, u0b);
  k_subm_m<32, 32, 32, 7, 7, 32><<<dim3(2048), TPB, 0, stream>>>(u0b, e0b, pw_dec0, bn_dec0, list0, cnt0, zb, c0b);
  // head
  k_head_b<<<g(524288LL * 45), TPB, 0, stream>>>(c0b, w_head, b_head, list0, cnt0, (float*)d_out);
}